// Round 1
// baseline (412.735 us; speedup 1.0000x reference)
//
#include <hip/hip_runtime.h>

typedef unsigned short ushort;

typedef __bf16 bf16x8 __attribute__((ext_vector_type(8)));
typedef float  f32x4  __attribute__((ext_vector_type(4)));
typedef unsigned short u16x8 __attribute__((ext_vector_type(8)));
typedef unsigned short u16x4 __attribute__((ext_vector_type(4)));
typedef unsigned int   u32x2 __attribute__((ext_vector_type(2)));

static constexpr int BB   = 32;
static constexpr int NN   = 577;   // N = NP+1
static constexpr int LL   = 576;   // NP
static constexpr int DIMC = 512;
static constexpr int BN   = BB * NN;  // 18464

// ---------------- workspace arena (bytes), total 98,828,288 (~94.3 MB) -----
// y1 (fp32 EMA fwd) lives in d_out; y2 (fp32 EMA bwd) lives in the QK region
// (dead until k_qkv writes it, after k_ema_comb consumed y2).
static constexpr size_t SZ_WQKVT = 1536ull * 512 * 2;
static constexpr size_t SZ_WOUTT = 512ull * 512 * 2;
static constexpr size_t SZ_QK    = (size_t)BN * 1024 * 2;    // 37,814,272
static constexpr size_t SZ_V     = (size_t)BN * 512 * 2;     // 18,907,136
static constexpr size_t SZ_VT    = 256ull * 64 * 640 * 2;    // 20,971,520
static constexpr size_t OFF_WQKVT = 0;
static constexpr size_t OFF_WOUTT = OFF_WQKVT + SZ_WQKVT;
static constexpr size_t OFF_QTAB  = OFF_WOUTT + SZ_WOUTT;
static constexpr size_t OFF_CTAB  = OFF_QTAB + 65536;
static constexpr size_t OFF_QK    = OFF_CTAB + 65536;
static constexpr size_t OFF_V     = OFF_QK + SZ_QK;
static constexpr size_t OFF_REGION= OFF_V + SZ_V;
static constexpr size_t OFF_XM    = OFF_REGION;              // xm dead after k_qkv
static constexpr size_t OFF_VT    = OFF_REGION;              // vt overlays xm
static constexpr size_t OFF_AO    = OFF_REGION + SZ_VT;
static constexpr size_t WS_NEEDED = OFF_AO + SZ_V;           // 98,828,288

// ---------------- helpers ----------------
__device__ __forceinline__ ushort bf16bits(float f) {
  unsigned int u = __builtin_bit_cast(unsigned int, f);
  u = (u + 0x7fffu + ((u >> 16) & 1u)) >> 16;
  return (ushort)u;
}
__device__ __forceinline__ float sigmoidf_(float z) { return 1.f / (1.f + __expf(-z)); }
__device__ __forceinline__ float siluf(float z)     { return z / (1.f + __expf(-z)); }

// ---------------- prep: EMA tables + bf16 transposed weights ----------------
__global__ __launch_bounds__(256) void k_prep(
    const float* __restrict__ delta, const float* __restrict__ alpha,
    const float* __restrict__ beta,  const float* __restrict__ gamma,
    const float* __restrict__ Wqk,   const float* __restrict__ Wv,
    const float* __restrict__ Wout,
    float* __restrict__ qtab, float* __restrict__ ctab,
    ushort* __restrict__ Wqkvt, ushort* __restrict__ Woutt)
{
  int idx = blockIdx.x * 256 + threadIdx.x;
  if (idx < 16384) {
    float p = sigmoidf_(delta[idx]);
    float q = 1.f - p * sigmoidf_(alpha[idx]);
    qtab[idx] = q;
    ctab[idx] = p * beta[idx] * gamma[idx] * 0.25f;   // scale = sqrt(1/16)
  }
  int i2 = idx - 16384;                                // Wqkv_t: [1536][512]
  if (i2 >= 0 && i2 < 1536 * 512) {
    int n = i2 >> 9, k = i2 & 511;
    float w = (n < 1024) ? Wqk[k * 1024 + n] : Wv[k * 512 + (n - 1024)];
    Wqkvt[i2] = bf16bits(w);
  }
  int i3 = i2 - 1536 * 512;                            // Wout_t: [512][512]
  if (i3 >= 0 && i3 < 512 * 512) {
    int n = i3 >> 9, k = i3 & 511;
    Woutt[i3] = bf16bits(Wout[k * 512 + n]);
  }
}

// -------- EMA dual scan: fwd (blocks 0-7) -> y1, bwd (blocks 8-15) -> y2 ----
// Independent directions run concurrently: 512 waves instead of 2x256 serial.
__global__ __launch_bounds__(64) void k_ema_scan(
    const float* __restrict__ x, const float* __restrict__ qtab,
    const float* __restrict__ ctab, float* __restrict__ y1, float* __restrict__ y2)
{
  const int bx = blockIdx.x;
  const int b  = blockIdx.y;
  if (bx < 8) {
    const int d = bx * 64 + threadIdx.x;
    float q[16], c[16], h[16];
    #pragma unroll
    for (int n = 0; n < 16; ++n) { q[n] = qtab[d*16+n]; c[n] = ctab[d*16+n]; h[n] = 0.f; }
    const float* xp = x  + ((size_t)b * NN + 1) * DIMC + d;
    float*       yp = y1 + ((size_t)b * LL)     * DIMC + d;
    float xn[8];
    #pragma unroll
    for (int u = 0; u < 8; ++u) xn[u] = xp[u * DIMC];
    for (int blk = 0; blk < 72; ++blk) {
      float xv[8];
      #pragma unroll
      for (int u = 0; u < 8; ++u) xv[u] = xn[u];
      if (blk < 71) {
        #pragma unroll
        for (int u = 0; u < 8; ++u) xn[u] = xp[((blk + 1) * 8 + u) * DIMC];
      }
      #pragma unroll
      for (int u = 0; u < 8; ++u) {
        float xx = xv[u], y = 0.f;
        #pragma unroll
        for (int n = 0; n < 16; ++n) { h[n] = fmaf(q[n], h[n], xx); y = fmaf(c[n], h[n], y); }
        yp[(blk * 8 + u) * DIMC] = y;
      }
    }
  } else {
    const int d = (bx - 8) * 64 + threadIdx.x;
    float q[16], c[16], g[16];
    #pragma unroll
    for (int n = 0; n < 16; ++n) { q[n] = qtab[(d+512)*16+n]; c[n] = ctab[(d+512)*16+n]; g[n] = 0.f; }
    const float* xp = x  + ((size_t)b * NN + 1) * DIMC + d;
    float*       yp = y2 + ((size_t)b * LL)     * DIMC + d;
    float xn[8];
    #pragma unroll
    for (int u = 0; u < 8; ++u) xn[u] = xp[(568 + u) * DIMC];
    for (int blk = 71; blk >= 0; --blk) {
      float xv[8];
      #pragma unroll
      for (int u = 0; u < 8; ++u) xv[u] = xn[u];
      if (blk > 0) {
        #pragma unroll
        for (int u = 0; u < 8; ++u) xn[u] = xp[((blk - 1) * 8 + u) * DIMC];
      }
      #pragma unroll
      for (int u = 7; u >= 0; --u) {
        float xx = xv[u], y = 0.f;
        #pragma unroll
        for (int n = 0; n < 16; ++n) { g[n] = fmaf(q[n], g[n], xx); y = fmaf(c[n], g[n], y); }
        yp[(blk * 8 + u) * DIMC] = y;
      }
    }
  }
}

// -------- combine: xm = bf16(silu(y1+y2+x*omega)); cls row passthrough ------
__global__ __launch_bounds__(256) void k_ema_comb(
    const float* __restrict__ x, const float* __restrict__ y1,
    const float* __restrict__ y2, const float* __restrict__ omega,
    ushort* __restrict__ xm)
{
  size_t v = (size_t)blockIdx.x * 256 + threadIdx.x;   // vec4 index
  size_t e = v * 4;
  int n = (int)(e >> 9);
  int d = (int)(e & 511);
  int b = n / 577;
  int i = n - b * 577;
  f32x4 xv = *(const f32x4*)(x + e);
  u16x4 o;
  if (i == 0) {
    #pragma unroll
    for (int k = 0; k < 4; ++k) o[k] = bf16bits(xv[k]);
  } else {
    size_t ey = ((size_t)b * LL + (i - 1)) * DIMC + d;
    f32x4 a  = *(const f32x4*)(y1 + ey);
    f32x4 c2 = *(const f32x4*)(y2 + ey);
    f32x4 om = *(const f32x4*)(omega + d);
    #pragma unroll
    for (int k = 0; k < 4; ++k) o[k] = bf16bits(siluf(a[k] + c2[k] + xv[k] * om[k]));
  }
  *(u16x4*)(xm + e) = o;
}

// ---------------- QKV GEMM: xm[18464,512] @ Wqkv_t[1536,512]^T -------------
// q columns (n0<512) pre-scaled by 0.125 for attention. Rows padded 32->40
// ushorts (80 B) to stagger LDS banks (2-way, free).
// XCD-chunked block remap (bijective, nwg=1740): the 12 n-tiles sharing an
// A-row-panel are consecutive within one XCD chunk -> A panel stays in its L2.
__global__ __launch_bounds__(256) void k_qkv(
    const ushort* __restrict__ A, const ushort* __restrict__ Bt,
    ushort* __restrict__ qk, ushort* __restrict__ v)
{
  __shared__ alignas(16) ushort lA[128 * 40];
  __shared__ alignas(16) ushort lB[128 * 40];
  const int tid = threadIdx.x, wv = tid >> 6, lane = tid & 63;
  const int quad = lane >> 4, c16 = lane & 15;
  const int fid = blockIdx.y * 12 + blockIdx.x;        // dispatch-order id
  const int xcd = fid & 7, ord = fid >> 3;             // nwg=1740: q=217,r=4
  const int wg  = (xcd < 4 ? xcd * 218 : 872 + (xcd - 4) * 217) + ord;
  const int row0 = (wg / 12) * 128, n0 = (wg % 12) * 128;
  const int wm = (wv >> 1) * 64, wn = (wv & 1) * 64;
  f32x4 z4 = {0.f, 0.f, 0.f, 0.f};
  f32x4 acc[4][4];
  #pragma unroll
  for (int mi = 0; mi < 4; ++mi)
    #pragma unroll
    for (int ni = 0; ni < 4; ++ni) acc[mi][ni] = z4;

  for (int kt = 0; kt < 16; ++kt) {
    const int k0 = kt * 32;
    u16x8 sa[2], sb[2];
    #pragma unroll
    for (int it = 0; it < 2; ++it) {
      int ch = it * 256 + tid;
      int r = ch >> 2, cc = ch & 3;
      int grow = row0 + r; if (grow > BN - 1) grow = BN - 1;
      sa[it] = *(const u16x8*)(A + (size_t)grow * 512 + k0 + cc * 8);
      sb[it] = *(const u16x8*)(Bt + (size_t)(n0 + r) * 512 + k0 + cc * 8);
    }
    __syncthreads();
    #pragma unroll
    for (int it = 0; it < 2; ++it) {
      int ch = it * 256 + tid;
      int r = ch >> 2, cc = ch & 3;
      *(u16x8*)(lA + r * 40 + cc * 8) = sa[it];
      *(u16x8*)(lB + r * 40 + cc * 8) = sb[it];
    }
    __syncthreads();
    bf16x8 af[4], bfv[4];
    #pragma unroll
    for (int mi = 0; mi < 4; ++mi)
      af[mi] = *(const bf16x8*)(lA + (wm + mi * 16 + c16) * 40 + quad * 8);
    #pragma unroll
    for (int ni = 0; ni < 4; ++ni)
      bfv[ni] = *(const bf16x8*)(lB + (wn + ni * 16 + c16) * 40 + quad * 8);
    #pragma unroll
    for (int mi = 0; mi < 4; ++mi)
      #pragma unroll
      for (int ni = 0; ni < 4; ++ni)
        acc[mi][ni] = __builtin_amdgcn_mfma_f32_16x16x32_bf16(af[mi], bfv[ni], acc[mi][ni], 0, 0, 0);
  }
  const bool isv = (n0 >= 1024);
  const float osc = (n0 < 512) ? 0.125f : 1.0f;      // fold 1/sqrt(DH) into q
  #pragma unroll
  for (int mi = 0; mi < 4; ++mi) {
    #pragma unroll
    for (int r = 0; r < 4; ++r) {
      int grow = row0 + wm + mi * 16 + quad * 4 + r;
      if (grow < BN) {
        #pragma unroll
        for (int ni = 0; ni < 4; ++ni) {
          int col = n0 + wn + ni * 16 + c16;
          ushort vb = bf16bits(acc[mi][ni][r] * osc);
          if (!isv) qk[(size_t)grow * 1024 + col] = vb;
          else      v[(size_t)grow * 512 + (col - 1024)] = vb;
        }
      }
    }
  }
}

// ---------------- transpose v -> vt[bh*64+dh][640] (zero-padded j>=577) ----
__global__ __launch_bounds__(256) void k_vtrans(
    const ushort* __restrict__ v, ushort* __restrict__ vt)
{
  __shared__ alignas(16) ushort lt[64 * 72];
  const int tid = threadIdx.x;
  const int bh = blockIdx.y, b = bh >> 3, h = bh & 7;
  const int j0 = blockIdx.x * 64;
  #pragma unroll
  for (int pass = 0; pass < 2; ++pass) {
    int cch = pass * 256 + tid;
    int jl = cch >> 3, cc = cch & 7;
    int gj = j0 + jl;
    u16x8 val = {0, 0, 0, 0, 0, 0, 0, 0};
    if (gj < 577) val = *(const u16x8*)(v + ((size_t)(b * NN + gj)) * 512 + h * 64 + cc * 8);
    *(u16x8*)(lt + jl * 72 + cc * 8) = val;
  }
  __syncthreads();
  #pragma unroll
  for (int pass = 0; pass < 2; ++pass) {
    int cch = pass * 256 + tid;
    int dh = cch >> 3, jc = cch & 7;
    u16x8 o;
    #pragma unroll
    for (int e = 0; e < 8; ++e) o[e] = lt[(jc * 8 + e) * 72 + dh];
    *(u16x8*)(vt + ((size_t)(bh * 64 + dh)) * 640 + j0 + jc * 8) = o;
  }
}

// -------- fused flash attention: O = softmax(QK^T) V + Bias V --------------
// Static softmax (scores bounded ~|50| << 88 -> raw exp safe in fp32).
// Swapped QK^T (mfma(K,Q) -> S^T): a lane's 4 acc values are 4 CONSECUTIVE
// P columns of one row -> packed v_cvt_pk_bf16_f32 + single ds_write_b64
// (replaces 32 scalar u16 LDS writes + 32 bf16bits per thread per tile).
// Q lives in registers (lq LDS dropped: 50.5->34.5 KB, 4 blocks/CU with
// launch_bounds(256,4)). Next K/V tile loads issue at PV start: latency
// hides under PV, drained at next loop-top barrier.
// Grid (bh, itile): 256 % 8 == 0 -> all 5 i-tiles of a bh land on one XCD
// (K/V tiles stay in that XCD's L2).
__global__ __launch_bounds__(256, 4) void k_fattn(
    const ushort* __restrict__ qk, const ushort* __restrict__ vt,
    const float* __restrict__ relb, ushort* __restrict__ ao)
{
  __shared__ alignas(16) ushort lk[64 * 64];
  __shared__ alignas(16) ushort lv[64 * 64];
  __shared__ alignas(16) ushort lp[128 * 64];
  __shared__ ushort lbias16[1280];     // bf16 bias at +64 offset, pad-safe
  const int tid = threadIdx.x, wv = tid >> 6, lane = tid & 63;
  const int quad = lane >> 4, c16 = lane & 15;
  const int bh = blockIdx.x, b = bh >> 3, h = bh & 7;
  const int i0 = blockIdx.y * 128, wm = wv * 32;
  for (int t = tid; t < 1280; t += 256) {
    int idx = t - 64;
    lbias16[t] = (idx >= 0 && idx < 1153) ? bf16bits(relb[idx]) : (ushort)0;
  }
  // Q fragments in registers for the whole block (rows wm+ms*16+c16)
  bf16x8 aq[2][2];
  #pragma unroll
  for (int ms = 0; ms < 2; ++ms) {
    int gi = i0 + wm + ms * 16 + c16; if (gi > 576) gi = 576;
    const ushort* qp = qk + ((size_t)(b * NN + gi)) * 1024 + h * 64;
    #pragma unroll
    for (int kk = 0; kk < 2; ++kk)
      aq[ms][kk] = *(const bf16x8*)(qp + (kk * 4 + quad) * 8);
  }
  const int s_r = tid >> 3, s_c = tid & 7;
  const ushort* kbase = qk + ((size_t)b * NN) * 1024 + 512 + h * 64 + s_c * 8;
  const ushort* vbase = vt + ((size_t)bh * 64) * 640 + s_c * 8;

  float lsum[2] = {0.f, 0.f};
  f32x4 z4 = {0.f, 0.f, 0.f, 0.f};
  f32x4 accp[2][4], accb[2][4];
  #pragma unroll
  for (int ms = 0; ms < 2; ++ms)
    #pragma unroll
    for (int ns = 0; ns < 4; ++ns) { accp[ms][ns] = z4; accb[ms][ns] = z4; }

  // preload tile jt=0 (j = 0..63, no clamp needed)
  u16x8 sk[2], sv[2];
  #pragma unroll
  for (int it = 0; it < 2; ++it) {
    int r = it * 32 + s_r;
    sk[it] = *(const u16x8*)(kbase + (size_t)r * 1024);
    sv[it] = *(const u16x8*)(vbase + (size_t)r * 640);
  }

  for (int jt = 0; jt < 10; ++jt) {
    __syncthreads();                       // prior lk/lv/lp readers done (+ drains prefetch)
    #pragma unroll
    for (int it = 0; it < 2; ++it) {
      int r = it * 32 + s_r;
      int pc = (s_c ^ (r & 7)) * 8;
      *(u16x8*)(lk + r * 64 + pc) = sk[it];
      *(u16x8*)(lv + r * 64 + pc) = sv[it];
    }
    __syncthreads();                       // staging visible
    // ---- S^T = K Q^T, one ms (16 q-rows) at a time; softmax fused per ms
    #pragma unroll
    for (int ms = 0; ms < 2; ++ms) {
      f32x4 dacc[4] = {z4, z4, z4, z4};
      #pragma unroll
      for (int kk = 0; kk < 2; ++kk) {
        const int ck = kk * 4 + quad;
        #pragma unroll
        for (int ns = 0; ns < 4; ++ns) {
          const int row = ns * 16 + c16;
          bf16x8 bk = *(const bf16x8*)(lk + row * 64 + ((ck ^ (row & 7)) * 8));
          dacc[ns] = __builtin_amdgcn_mfma_f32_16x16x32_bf16(bk, aq[ms][kk], dacc[ns], 0, 0, 0);
        }
      }
      // lane holds S[i = wm+ms*16+c16][j = j0 + ns*16 + quad*4 + r]
      const int irow = wm + ms * 16 + c16;
      const int xr = irow & 7;
      #pragma unroll
      for (int ns = 0; ns < 4; ++ns) {
        float ex[4];
        #pragma unroll
        for (int r = 0; r < 4; ++r) {
          float e = __expf(dacc[ns][r]);
          if (jt == 9 && (ns * 16 + quad * 4 + r) >= 1) e = 0.f;   // j >= 577
          ex[r] = e;
        }
        lsum[ms] += (ex[0] + ex[1]) + (ex[2] + ex[3]);
        unsigned int p0, p1;
        asm("v_cvt_pk_bf16_f32 %0, %1, %2" : "=v"(p0) : "v"(ex[0]), "v"(ex[1]));
        asm("v_cvt_pk_bf16_f32 %0, %1, %2" : "=v"(p1) : "v"(ex[2]), "v"(ex[3]));
        u32x2 pw = {p0, p1};
        const int lc = ns * 2 + (quad >> 1);         // logical 8-col chunk
        *(u32x2*)(lp + irow * 64 + ((lc ^ xr) * 8) + (quad & 1) * 4) = pw;
      }
    }
    __syncthreads();                       // lp visible
    // issue next K/V tile loads now: latency hides under PV below
    if (jt < 9) {
      const int j0n = (jt + 1) * 64;
      #pragma unroll
      for (int it = 0; it < 2; ++it) {
        int r = it * 32 + s_r;
        int gj = j0n + r; if (gj > 576) gj = 576;
        sk[it] = *(const u16x8*)(kbase + (size_t)gj * 1024);
        sv[it] = *(const u16x8*)(vbase + (size_t)r * 640 + j0n);
      }
    }
    // ---- O += P~ V  and  O_b += Bias V
    const int j0 = jt * 64;
    #pragma unroll
    for (int kk = 0; kk < 2; ++kk) {
      const int ck = kk * 4 + quad;
      bf16x8 ap[2], ab[2];
      #pragma unroll
      for (int ms = 0; ms < 2; ++ms) {
        const int row = wm + ms * 16 + c16;
        ap[ms] = *(const bf16x8*)(lp + row * 64 + ((ck ^ (row & 7)) * 8));
        u16x8 abu;
        const int base = 64 + 576 + j0 + kk * 32 + quad * 8 - (i0 + row);
        #pragma unroll
        for (int e = 0; e < 8; ++e) abu[e] = lbias16[base + e];
        ab[ms] = __builtin_bit_cast(bf16x8, abu);
      }
      #pragma unroll
      for (int ns = 0; ns < 4; ++ns) {
        const int row = ns * 16 + c16;
        bf16x8 bV = *(const bf16x8*)(lv + row * 64 + ((ck ^ (row & 7)) * 8));
        #pragma unroll
        for (int ms = 0; ms < 2; ++ms) {
          accp[ms][ns] = __builtin_amdgcn_mfma_f32_16x16x32_bf16(ap[ms], bV, accp[ms][ns], 0, 0, 0);
          accb[ms][ns] = __builtin_amdgcn_mfma_f32_16x16x32_bf16(ab[ms], bV, accb[ms][ns], 0, 0, 0);
        }
      }
    }
  }
  // ---- epilogue: row sums live per-lane for row c16; reduce across quads,
  // then shfl the needed row's total (rows quad*4+r of the output C-layout).
  float tot[2];
  #pragma unroll
  for (int ms = 0; ms < 2; ++ms) {
    float t = lsum[ms];
    t += __shfl_xor(t, 16);
    t += __shfl_xor(t, 32);
    tot[ms] = t;
  }
  #pragma unroll
  for (int ms = 0; ms < 2; ++ms) {
    #pragma unroll
    for (int r = 0; r < 4; ++r) {
      float li = 1.f / __shfl(tot[ms], quad * 4 + r);
      int ii = i0 + wm + ms * 16 + quad * 4 + r;
      if (ii < 577) {
        #pragma unroll
        for (int ns = 0; ns < 4; ++ns)
          ao[((size_t)(b * NN + ii)) * 512 + h * 64 + ns * 16 + c16] =
              bf16bits(accp[ms][ns][r] * li + accb[ms][ns][r]);
      }
    }
  }
}

// ---------------- out GEMM: ao[18464,512] @ Wout_t[512,512]^T + b_out -----
__global__ __launch_bounds__(256) void k_out(
    const ushort* __restrict__ A, const ushort* __restrict__ Bt,
    const float* __restrict__ bout, float* __restrict__ out)
{
  __shared__ alignas(16) ushort lA[128 * 40];
  __shared__ alignas(16) ushort lB[128 * 40];
  const int tid = threadIdx.x, wv = tid >> 6, lane = tid & 63;
  const int quad = lane >> 4, c16 = lane & 15;
  const int row0 = blockIdx.y * 128, n0 = blockIdx.x * 128;
  const int wm = (wv >> 1) * 64, wn = (wv & 1) * 64;
  f32x4 z4 = {0.f, 0.f, 0.f, 0.f};
  f32x4 acc[4][4];
  #pragma unroll
  for (int mi = 0; mi < 4; ++mi)
    #pragma unroll
    for (int ni = 0; ni < 4; ++ni) acc[mi][ni] = z4;

  for (int kt = 0; kt < 16; ++kt) {
    const int k0 = kt * 32;
    u16x8 sa[2], sb[2];
    #pragma unroll
    for (int it = 0; it < 2; ++it) {
      int ch = it * 256 + tid;
      int r = ch >> 2, cc = ch & 3;
      int grow = row0 + r; if (grow > BN - 1) grow = BN - 1;
      sa[it] = *(const u16x8*)(A + (size_t)grow * 512 + k0 + cc * 8);
      sb[it] = *(const u16x8*)(Bt + (size_t)(n0 + r) * 512 + k0 + cc * 8);
    }
    __syncthreads();
    #pragma unroll
    for (int it = 0; it < 2; ++it) {
      int ch = it * 256 + tid;
      int r = ch >> 2, cc = ch & 3;
      *(u16x8*)(lA + r * 40 + cc * 8) = sa[it];
      *(u16x8*)(lB + r * 40 + cc * 8) = sb[it];
    }
    __syncthreads();
    bf16x8 af[4], bfv[4];
    #pragma unroll
    for (int mi = 0; mi < 4; ++mi)
      af[mi] = *(const bf16x8*)(lA + (wm + mi * 16 + c16) * 40 + quad * 8);
    #pragma unroll
    for (int ni = 0; ni < 4; ++ni)
      bfv[ni] = *(const bf16x8*)(lB + (wn + ni * 16 + c16) * 40 + quad * 8);
    #pragma unroll
    for (int mi = 0; mi < 4; ++mi)
      #pragma unroll
      for (int ni = 0; ni < 4; ++ni)
        acc[mi][ni] = __builtin_amdgcn_mfma_f32_16x16x32_bf16(af[mi], bfv[ni], acc[mi][ni], 0, 0, 0);
  }
  #pragma unroll
  for (int mi = 0; mi < 4; ++mi) {
    #pragma unroll
    for (int r = 0; r < 4; ++r) {
      int grow = row0 + wm + mi * 16 + quad * 4 + r;
      if (grow < BN) {
        #pragma unroll
        for (int ni = 0; ni < 4; ++ni) {
          int col = n0 + wn + ni * 16 + c16;
          out[(size_t)grow * 512 + col] = acc[mi][ni][r] + bout[col];
        }
      }
    }
  }
}

// ---------------- launch ----------------
extern "C" void kernel_launch(void* const* d_in, const int* in_sizes, int n_in,
                              void* d_out, int out_size, void* d_ws, size_t ws_size,
                              hipStream_t stream) {
  (void)in_sizes; (void)n_in; (void)out_size;
  if (ws_size < WS_NEEDED) return;   // fail clean, not crash
  const float* x    = (const float*)d_in[0];
  const float* Wqk  = (const float*)d_in[1];
  const float* Wv   = (const float*)d_in[2];
  const float* Wout = (const float*)d_in[3];
  const float* bout = (const float*)d_in[4];
  const float* relb = (const float*)d_in[5];
  const float* edel = (const float*)d_in[6];
  const float* ealp = (const float*)d_in[7];
  const float* ebet = (const float*)d_in[8];
  const float* egam = (const float*)d_in[9];
  const float* eome = (const float*)d_in[10];

  char* ws = (char*)d_ws;
  ushort* Wqkvt = (ushort*)(ws + OFF_WQKVT);
  ushort* Woutt = (ushort*)(ws + OFF_WOUTT);
  float*  qtab  = (float*)(ws + OFF_QTAB);
  float*  ctab  = (float*)(ws + OFF_CTAB);
  ushort* qkb   = (ushort*)(ws + OFF_QK);
  ushort* vb    = (ushort*)(ws + OFF_V);
  ushort* xm    = (ushort*)(ws + OFF_XM);
  ushort* vtb   = (ushort*)(ws + OFF_VT);
  ushort* aob   = (ushort*)(ws + OFF_AO);
  float*  outp  = (float*)d_out;
  float*  y1    = outp;                        // d_out as fp32 scratch
  float*  y2    = (float*)(ws + OFF_QK);       // QK region dead until k_qkv

  k_prep<<<dim3(4160), dim3(256), 0, stream>>>(edel, ealp, ebet, egam, Wqk, Wv, Wout,
                                               qtab, ctab, Wqkvt, Woutt);
  k_ema_scan<<<dim3(16, 32), dim3(64), 0, stream>>>(x, qtab, ctab, y1, y2);
  k_ema_comb<<<dim3(9232), dim3(256), 0, stream>>>(x, y1, y2, eome, xm);
  k_qkv<<<dim3(12, 145), dim3(256), 0, stream>>>(xm, Wqkvt, qkb, vb);
  k_vtrans<<<dim3(10, 256), dim3(256), 0, stream>>>(vb, vtb);
  k_fattn<<<dim3(256, 5), dim3(256), 0, stream>>>(qkb, vtb, relb, aob);
  k_out<<<dim3(4, 145), dim3(256), 0, stream>>>(aob, Woutt, bout, outp);
}

// Round 3
// 356.838 us; speedup vs baseline: 1.1566x; 1.1566x over previous
//
#include <hip/hip_runtime.h>

typedef unsigned short ushort;

typedef __bf16 bf16x8 __attribute__((ext_vector_type(8)));
typedef float  f32x4  __attribute__((ext_vector_type(4)));
typedef unsigned short u16x8 __attribute__((ext_vector_type(8)));
typedef unsigned short u16x4 __attribute__((ext_vector_type(4)));
typedef unsigned int   u32x2 __attribute__((ext_vector_type(2)));

static constexpr int BB   = 32;
static constexpr int NN   = 577;   // N = NP+1
static constexpr int LL   = 576;   // NP
static constexpr int DIMC = 512;
static constexpr int BN   = BB * NN;  // 18464

// ---------------- workspace arena (bytes), total 98,828,288 (~94.3 MB) -----
// y1 (fp32 EMA fwd) lives in d_out; y2 (fp32 EMA bwd) lives in the QK region
// (dead until k_qkv writes it, after k_ema_comb consumed y2).
static constexpr size_t SZ_WQKVT = 1536ull * 512 * 2;
static constexpr size_t SZ_WOUTT = 512ull * 512 * 2;
static constexpr size_t SZ_QK    = (size_t)BN * 1024 * 2;    // 37,814,272
static constexpr size_t SZ_V     = (size_t)BN * 512 * 2;     // 18,907,136
static constexpr size_t SZ_VT    = 256ull * 64 * 640 * 2;    // 20,971,520
static constexpr size_t OFF_WQKVT = 0;
static constexpr size_t OFF_WOUTT = OFF_WQKVT + SZ_WQKVT;
static constexpr size_t OFF_QTAB  = OFF_WOUTT + SZ_WOUTT;
static constexpr size_t OFF_CTAB  = OFF_QTAB + 65536;
static constexpr size_t OFF_QK    = OFF_CTAB + 65536;
static constexpr size_t OFF_V     = OFF_QK + SZ_QK;
static constexpr size_t OFF_REGION= OFF_V + SZ_V;
static constexpr size_t OFF_XM    = OFF_REGION;              // xm dead after k_qkv
static constexpr size_t OFF_VT    = OFF_REGION;              // vt overlays xm
static constexpr size_t OFF_AO    = OFF_REGION + SZ_VT;
static constexpr size_t WS_NEEDED = OFF_AO + SZ_V;           // 98,828,288

// ---------------- helpers ----------------
__device__ __forceinline__ ushort bf16bits(float f) {
  unsigned int u = __builtin_bit_cast(unsigned int, f);
  u = (u + 0x7fffu + ((u >> 16) & 1u)) >> 16;
  return (ushort)u;
}
__device__ __forceinline__ float sigmoidf_(float z) { return 1.f / (1.f + __expf(-z)); }
__device__ __forceinline__ float siluf(float z)     { return z / (1.f + __expf(-z)); }

// ---------------- prep: EMA tables + bf16 transposed weights ----------------
__global__ __launch_bounds__(256) void k_prep(
    const float* __restrict__ delta, const float* __restrict__ alpha,
    const float* __restrict__ beta,  const float* __restrict__ gamma,
    const float* __restrict__ Wqk,   const float* __restrict__ Wv,
    const float* __restrict__ Wout,
    float* __restrict__ qtab, float* __restrict__ ctab,
    ushort* __restrict__ Wqkvt, ushort* __restrict__ Woutt)
{
  int idx = blockIdx.x * 256 + threadIdx.x;
  if (idx < 16384) {
    float p = sigmoidf_(delta[idx]);
    float q = 1.f - p * sigmoidf_(alpha[idx]);
    qtab[idx] = q;
    ctab[idx] = p * beta[idx] * gamma[idx] * 0.25f;   // scale = sqrt(1/16)
  }
  int i2 = idx - 16384;                                // Wqkv_t: [1536][512]
  if (i2 >= 0 && i2 < 1536 * 512) {
    int n = i2 >> 9, k = i2 & 511;
    float w = (n < 1024) ? Wqk[k * 1024 + n] : Wv[k * 512 + (n - 1024)];
    Wqkvt[i2] = bf16bits(w);
  }
  int i3 = i2 - 1536 * 512;                            // Wout_t: [512][512]
  if (i3 >= 0 && i3 < 512 * 512) {
    int n = i3 >> 9, k = i3 & 511;
    Woutt[i3] = bf16bits(Wout[k * 512 + n]);
  }
}

// -------- EMA dual scan: fwd (blocks 0-7) -> y1, bwd (blocks 8-15) -> y2 ----
// Independent directions run concurrently: 512 waves instead of 2x256 serial.
__global__ __launch_bounds__(64) void k_ema_scan(
    const float* __restrict__ x, const float* __restrict__ qtab,
    const float* __restrict__ ctab, float* __restrict__ y1, float* __restrict__ y2)
{
  const int bx = blockIdx.x;
  const int b  = blockIdx.y;
  if (bx < 8) {
    const int d = bx * 64 + threadIdx.x;
    float q[16], c[16], h[16];
    #pragma unroll
    for (int n = 0; n < 16; ++n) { q[n] = qtab[d*16+n]; c[n] = ctab[d*16+n]; h[n] = 0.f; }
    const float* xp = x  + ((size_t)b * NN + 1) * DIMC + d;
    float*       yp = y1 + ((size_t)b * LL)     * DIMC + d;
    float xn[8];
    #pragma unroll
    for (int u = 0; u < 8; ++u) xn[u] = xp[u * DIMC];
    for (int blk = 0; blk < 72; ++blk) {
      float xv[8];
      #pragma unroll
      for (int u = 0; u < 8; ++u) xv[u] = xn[u];
      if (blk < 71) {
        #pragma unroll
        for (int u = 0; u < 8; ++u) xn[u] = xp[((blk + 1) * 8 + u) * DIMC];
      }
      #pragma unroll
      for (int u = 0; u < 8; ++u) {
        float xx = xv[u], y = 0.f;
        #pragma unroll
        for (int n = 0; n < 16; ++n) { h[n] = fmaf(q[n], h[n], xx); y = fmaf(c[n], h[n], y); }
        yp[(blk * 8 + u) * DIMC] = y;
      }
    }
  } else {
    const int d = (bx - 8) * 64 + threadIdx.x;
    float q[16], c[16], g[16];
    #pragma unroll
    for (int n = 0; n < 16; ++n) { q[n] = qtab[(d+512)*16+n]; c[n] = ctab[(d+512)*16+n]; g[n] = 0.f; }
    const float* xp = x  + ((size_t)b * NN + 1) * DIMC + d;
    float*       yp = y2 + ((size_t)b * LL)     * DIMC + d;
    float xn[8];
    #pragma unroll
    for (int u = 0; u < 8; ++u) xn[u] = xp[(568 + u) * DIMC];
    for (int blk = 71; blk >= 0; --blk) {
      float xv[8];
      #pragma unroll
      for (int u = 0; u < 8; ++u) xv[u] = xn[u];
      if (blk > 0) {
        #pragma unroll
        for (int u = 0; u < 8; ++u) xn[u] = xp[((blk - 1) * 8 + u) * DIMC];
      }
      #pragma unroll
      for (int u = 7; u >= 0; --u) {
        float xx = xv[u], y = 0.f;
        #pragma unroll
        for (int n = 0; n < 16; ++n) { g[n] = fmaf(q[n], g[n], xx); y = fmaf(c[n], g[n], y); }
        yp[(blk * 8 + u) * DIMC] = y;
      }
    }
  }
}

// -------- combine: xm = bf16(silu(y1+y2+x*omega)); cls row passthrough ------
__global__ __launch_bounds__(256) void k_ema_comb(
    const float* __restrict__ x, const float* __restrict__ y1,
    const float* __restrict__ y2, const float* __restrict__ omega,
    ushort* __restrict__ xm)
{
  size_t v = (size_t)blockIdx.x * 256 + threadIdx.x;   // vec4 index
  size_t e = v * 4;
  int n = (int)(e >> 9);
  int d = (int)(e & 511);
  int b = n / 577;
  int i = n - b * 577;
  f32x4 xv = *(const f32x4*)(x + e);
  u16x4 o;
  if (i == 0) {
    #pragma unroll
    for (int k = 0; k < 4; ++k) o[k] = bf16bits(xv[k]);
  } else {
    size_t ey = ((size_t)b * LL + (i - 1)) * DIMC + d;
    f32x4 a  = *(const f32x4*)(y1 + ey);
    f32x4 c2 = *(const f32x4*)(y2 + ey);
    f32x4 om = *(const f32x4*)(omega + d);
    #pragma unroll
    for (int k = 0; k < 4; ++k) o[k] = bf16bits(siluf(a[k] + c2[k] + xv[k] * om[k]));
  }
  *(u16x4*)(xm + e) = o;
}

// ---------------- QKV GEMM: xm[18464,512] @ Wqkv_t[1536,512]^T -------------
// q columns (n0<512) pre-scaled by 0.125 for attention. Rows padded 32->40
// ushorts (80 B) to stagger LDS banks (2-way, free).
// XCD-chunked block remap (bijective, nwg=1740): the 12 n-tiles sharing an
// A-row-panel are consecutive within one XCD chunk -> A panel stays in its L2.
__global__ __launch_bounds__(256) void k_qkv(
    const ushort* __restrict__ A, const ushort* __restrict__ Bt,
    ushort* __restrict__ qk, ushort* __restrict__ v)
{
  __shared__ alignas(16) ushort lA[128 * 40];
  __shared__ alignas(16) ushort lB[128 * 40];
  const int tid = threadIdx.x, wv = tid >> 6, lane = tid & 63;
  const int quad = lane >> 4, c16 = lane & 15;
  const int fid = blockIdx.y * 12 + blockIdx.x;        // dispatch-order id
  const int xcd = fid & 7, ord = fid >> 3;             // nwg=1740: q=217,r=4
  const int wg  = (xcd < 4 ? xcd * 218 : 872 + (xcd - 4) * 217) + ord;
  const int row0 = (wg / 12) * 128, n0 = (wg % 12) * 128;
  const int wm = (wv >> 1) * 64, wn = (wv & 1) * 64;
  f32x4 z4 = {0.f, 0.f, 0.f, 0.f};
  f32x4 acc[4][4];
  #pragma unroll
  for (int mi = 0; mi < 4; ++mi)
    #pragma unroll
    for (int ni = 0; ni < 4; ++ni) acc[mi][ni] = z4;

  for (int kt = 0; kt < 16; ++kt) {
    const int k0 = kt * 32;
    u16x8 sa[2], sb[2];
    #pragma unroll
    for (int it = 0; it < 2; ++it) {
      int ch = it * 256 + tid;
      int r = ch >> 2, cc = ch & 3;
      int grow = row0 + r; if (grow > BN - 1) grow = BN - 1;
      sa[it] = *(const u16x8*)(A + (size_t)grow * 512 + k0 + cc * 8);
      sb[it] = *(const u16x8*)(Bt + (size_t)(n0 + r) * 512 + k0 + cc * 8);
    }
    __syncthreads();
    #pragma unroll
    for (int it = 0; it < 2; ++it) {
      int ch = it * 256 + tid;
      int r = ch >> 2, cc = ch & 3;
      *(u16x8*)(lA + r * 40 + cc * 8) = sa[it];
      *(u16x8*)(lB + r * 40 + cc * 8) = sb[it];
    }
    __syncthreads();
    bf16x8 af[4], bfv[4];
    #pragma unroll
    for (int mi = 0; mi < 4; ++mi)
      af[mi] = *(const bf16x8*)(lA + (wm + mi * 16 + c16) * 40 + quad * 8);
    #pragma unroll
    for (int ni = 0; ni < 4; ++ni)
      bfv[ni] = *(const bf16x8*)(lB + (wn + ni * 16 + c16) * 40 + quad * 8);
    #pragma unroll
    for (int mi = 0; mi < 4; ++mi)
      #pragma unroll
      for (int ni = 0; ni < 4; ++ni)
        acc[mi][ni] = __builtin_amdgcn_mfma_f32_16x16x32_bf16(af[mi], bfv[ni], acc[mi][ni], 0, 0, 0);
  }
  const bool isv = (n0 >= 1024);
  const float osc = (n0 < 512) ? 0.125f : 1.0f;      // fold 1/sqrt(DH) into q
  #pragma unroll
  for (int mi = 0; mi < 4; ++mi) {
    #pragma unroll
    for (int r = 0; r < 4; ++r) {
      int grow = row0 + wm + mi * 16 + quad * 4 + r;
      if (grow < BN) {
        #pragma unroll
        for (int ni = 0; ni < 4; ++ni) {
          int col = n0 + wn + ni * 16 + c16;
          ushort vb = bf16bits(acc[mi][ni][r] * osc);
          if (!isv) qk[(size_t)grow * 1024 + col] = vb;
          else      v[(size_t)grow * 512 + (col - 1024)] = vb;
        }
      }
    }
  }
}

// ---------------- transpose v -> vt[bh*64+dh][640] (zero-padded j>=577) ----
__global__ __launch_bounds__(256) void k_vtrans(
    const ushort* __restrict__ v, ushort* __restrict__ vt)
{
  __shared__ alignas(16) ushort lt[64 * 72];
  const int tid = threadIdx.x;
  const int bh = blockIdx.y, b = bh >> 3, h = bh & 7;
  const int j0 = blockIdx.x * 64;
  #pragma unroll
  for (int pass = 0; pass < 2; ++pass) {
    int cch = pass * 256 + tid;
    int jl = cch >> 3, cc = cch & 7;
    int gj = j0 + jl;
    u16x8 val = {0, 0, 0, 0, 0, 0, 0, 0};
    if (gj < 577) val = *(const u16x8*)(v + ((size_t)(b * NN + gj)) * 512 + h * 64 + cc * 8);
    *(u16x8*)(lt + jl * 72 + cc * 8) = val;
  }
  __syncthreads();
  #pragma unroll
  for (int pass = 0; pass < 2; ++pass) {
    int cch = pass * 256 + tid;
    int dh = cch >> 3, jc = cch & 7;
    u16x8 o;
    #pragma unroll
    for (int e = 0; e < 8; ++e) o[e] = lt[(jc * 8 + e) * 72 + dh];
    *(u16x8*)(vt + ((size_t)(bh * 64 + dh)) * 640 + j0 + jc * 8) = o;
  }
}

// -------- fused flash attention: O = softmax(QK^T) V + Bias V --------------
// Static softmax (scores bounded ~|50| << 88 -> raw exp safe in fp32).
// Swapped QK^T (mfma(K,Q) -> S^T): a lane's 4 acc values are 4 CONSECUTIVE
// P columns of one row -> RNE bit-pack (bf16bits, NOT v_cvt_pk_bf16_f32:
// the asm cvt rounds differently -> absmax 0.0078 -> 0.0406, round-2 fail)
// + single 8-byte LDS write (replaces 32 scalar u16 writes per tile).
// Q lives in registers (lq LDS dropped: 50.5->34.5 KB). No min-waves cap:
// launch_bounds(256,4) forced 128-reg budget -> accumulator spills (round 1:
// WRITE_SIZE 18->126 MB, dur 92->135 us). Allocator takes ~150 VGPRs.
// Next K/V tile loads issue at PV start: latency hides under PV, drained at
// next loop-top barrier.
// Grid (bh, itile): 256 % 8 == 0 -> all 5 i-tiles of a bh land on one XCD
// (K/V tiles stay in that XCD's L2).
__global__ __launch_bounds__(256) void k_fattn(
    const ushort* __restrict__ qk, const ushort* __restrict__ vt,
    const float* __restrict__ relb, ushort* __restrict__ ao)
{
  __shared__ alignas(16) ushort lk[64 * 64];
  __shared__ alignas(16) ushort lv[64 * 64];
  __shared__ alignas(16) ushort lp[128 * 64];
  __shared__ ushort lbias16[1280];     // bf16 bias at +64 offset, pad-safe
  const int tid = threadIdx.x, wv = tid >> 6, lane = tid & 63;
  const int quad = lane >> 4, c16 = lane & 15;
  const int bh = blockIdx.x, b = bh >> 3, h = bh & 7;
  const int i0 = blockIdx.y * 128, wm = wv * 32;
  for (int t = tid; t < 1280; t += 256) {
    int idx = t - 64;
    lbias16[t] = (idx >= 0 && idx < 1153) ? bf16bits(relb[idx]) : (ushort)0;
  }
  // Q fragments in registers for the whole block (rows wm+ms*16+c16)
  bf16x8 aq[2][2];
  #pragma unroll
  for (int ms = 0; ms < 2; ++ms) {
    int gi = i0 + wm + ms * 16 + c16; if (gi > 576) gi = 576;
    const ushort* qp = qk + ((size_t)(b * NN + gi)) * 1024 + h * 64;
    #pragma unroll
    for (int kk = 0; kk < 2; ++kk)
      aq[ms][kk] = *(const bf16x8*)(qp + (kk * 4 + quad) * 8);
  }
  const int s_r = tid >> 3, s_c = tid & 7;
  const ushort* kbase = qk + ((size_t)b * NN) * 1024 + 512 + h * 64 + s_c * 8;
  const ushort* vbase = vt + ((size_t)bh * 64) * 640 + s_c * 8;

  float lsum[2] = {0.f, 0.f};
  f32x4 z4 = {0.f, 0.f, 0.f, 0.f};
  f32x4 accp[2][4], accb[2][4];
  #pragma unroll
  for (int ms = 0; ms < 2; ++ms)
    #pragma unroll
    for (int ns = 0; ns < 4; ++ns) { accp[ms][ns] = z4; accb[ms][ns] = z4; }

  // preload tile jt=0 (j = 0..63, no clamp needed)
  u16x8 sk[2], sv[2];
  #pragma unroll
  for (int it = 0; it < 2; ++it) {
    int r = it * 32 + s_r;
    sk[it] = *(const u16x8*)(kbase + (size_t)r * 1024);
    sv[it] = *(const u16x8*)(vbase + (size_t)r * 640);
  }

  for (int jt = 0; jt < 10; ++jt) {
    __syncthreads();                       // prior lk/lv/lp readers done (+ drains prefetch)
    #pragma unroll
    for (int it = 0; it < 2; ++it) {
      int r = it * 32 + s_r;
      int pc = (s_c ^ (r & 7)) * 8;
      *(u16x8*)(lk + r * 64 + pc) = sk[it];
      *(u16x8*)(lv + r * 64 + pc) = sv[it];
    }
    __syncthreads();                       // staging visible
    // ---- S^T = K Q^T, one ms (16 q-rows) at a time; softmax fused per ms
    #pragma unroll
    for (int ms = 0; ms < 2; ++ms) {
      f32x4 dacc[4] = {z4, z4, z4, z4};
      #pragma unroll
      for (int kk = 0; kk < 2; ++kk) {
        const int ck = kk * 4 + quad;
        #pragma unroll
        for (int ns = 0; ns < 4; ++ns) {
          const int row = ns * 16 + c16;
          bf16x8 bk = *(const bf16x8*)(lk + row * 64 + ((ck ^ (row & 7)) * 8));
          dacc[ns] = __builtin_amdgcn_mfma_f32_16x16x32_bf16(bk, aq[ms][kk], dacc[ns], 0, 0, 0);
        }
      }
      // lane holds S[i = wm+ms*16+c16][j = j0 + ns*16 + quad*4 + r]
      const int irow = wm + ms * 16 + c16;
      const int xr = irow & 7;
      #pragma unroll
      for (int ns = 0; ns < 4; ++ns) {
        float ex[4];
        #pragma unroll
        for (int r = 0; r < 4; ++r) {
          float e = __expf(dacc[ns][r]);
          if (jt == 9 && (ns * 16 + quad * 4 + r) >= 1) e = 0.f;   // j >= 577
          ex[r] = e;
        }
        lsum[ms] += (ex[0] + ex[1]) + (ex[2] + ex[3]);
        unsigned int p0 = (unsigned int)bf16bits(ex[0]) | ((unsigned int)bf16bits(ex[1]) << 16);
        unsigned int p1 = (unsigned int)bf16bits(ex[2]) | ((unsigned int)bf16bits(ex[3]) << 16);
        u32x2 pw = {p0, p1};
        const int lc = ns * 2 + (quad >> 1);         // logical 8-col chunk
        *(u32x2*)(lp + irow * 64 + ((lc ^ xr) * 8) + (quad & 1) * 4) = pw;
      }
    }
    __syncthreads();                       // lp visible
    // issue next K/V tile loads now: latency hides under PV below
    if (jt < 9) {
      const int j0n = (jt + 1) * 64;
      #pragma unroll
      for (int it = 0; it < 2; ++it) {
        int r = it * 32 + s_r;
        int gj = j0n + r; if (gj > 576) gj = 576;
        sk[it] = *(const u16x8*)(kbase + (size_t)gj * 1024);
        sv[it] = *(const u16x8*)(vbase + (size_t)r * 640 + j0n);
      }
    }
    // ---- O += P~ V  and  O_b += Bias V
    const int j0 = jt * 64;
    #pragma unroll
    for (int kk = 0; kk < 2; ++kk) {
      const int ck = kk * 4 + quad;
      bf16x8 ap[2], ab[2];
      #pragma unroll
      for (int ms = 0; ms < 2; ++ms) {
        const int row = wm + ms * 16 + c16;
        ap[ms] = *(const bf16x8*)(lp + row * 64 + ((ck ^ (row & 7)) * 8));
        u16x8 abu;
        const int base = 64 + 576 + j0 + kk * 32 + quad * 8 - (i0 + row);
        #pragma unroll
        for (int e = 0; e < 8; ++e) abu[e] = lbias16[base + e];
        ab[ms] = __builtin_bit_cast(bf16x8, abu);
      }
      #pragma unroll
      for (int ns = 0; ns < 4; ++ns) {
        const int row = ns * 16 + c16;
        bf16x8 bV = *(const bf16x8*)(lv + row * 64 + ((ck ^ (row & 7)) * 8));
        #pragma unroll
        for (int ms = 0; ms < 2; ++ms) {
          accp[ms][ns] = __builtin_amdgcn_mfma_f32_16x16x32_bf16(ap[ms], bV, accp[ms][ns], 0, 0, 0);
          accb[ms][ns] = __builtin_amdgcn_mfma_f32_16x16x32_bf16(ab[ms], bV, accb[ms][ns], 0, 0, 0);
        }
      }
    }
  }
  // ---- epilogue: row sums live per-lane for row c16; reduce across quads,
  // then shfl the needed row's total (rows quad*4+r of the output C-layout).
  float tot[2];
  #pragma unroll
  for (int ms = 0; ms < 2; ++ms) {
    float t = lsum[ms];
    t += __shfl_xor(t, 16);
    t += __shfl_xor(t, 32);
    tot[ms] = t;
  }
  #pragma unroll
  for (int ms = 0; ms < 2; ++ms) {
    #pragma unroll
    for (int r = 0; r < 4; ++r) {
      float li = 1.f / __shfl(tot[ms], quad * 4 + r);
      int ii = i0 + wm + ms * 16 + quad * 4 + r;
      if (ii < 577) {
        #pragma unroll
        for (int ns = 0; ns < 4; ++ns)
          ao[((size_t)(b * NN + ii)) * 512 + h * 64 + ns * 16 + c16] =
              bf16bits(accp[ms][ns][r] * li + accb[ms][ns][r]);
      }
    }
  }
}

// ---------------- out GEMM: ao[18464,512] @ Wout_t[512,512]^T + b_out -----
__global__ __launch_bounds__(256) void k_out(
    const ushort* __restrict__ A, const ushort* __restrict__ Bt,
    const float* __restrict__ bout, float* __restrict__ out)
{
  __shared__ alignas(16) ushort lA[128 * 40];
  __shared__ alignas(16) ushort lB[128 * 40];
  const int tid = threadIdx.x, wv = tid >> 6, lane = tid & 63;
  const int quad = lane >> 4, c16 = lane & 15;
  const int row0 = blockIdx.y * 128, n0 = blockIdx.x * 128;
  const int wm = (wv >> 1) * 64, wn = (wv & 1) * 64;
  f32x4 z4 = {0.f, 0.f, 0.f, 0.f};
  f32x4 acc[4][4];
  #pragma unroll
  for (int mi = 0; mi < 4; ++mi)
    #pragma unroll
    for (int ni = 0; ni < 4; ++ni) acc[mi][ni] = z4;

  for (int kt = 0; kt < 16; ++kt) {
    const int k0 = kt * 32;
    u16x8 sa[2], sb[2];
    #pragma unroll
    for (int it = 0; it < 2; ++it) {
      int ch = it * 256 + tid;
      int r = ch >> 2, cc = ch & 3;
      int grow = row0 + r; if (grow > BN - 1) grow = BN - 1;
      sa[it] = *(const u16x8*)(A + (size_t)grow * 512 + k0 + cc * 8);
      sb[it] = *(const u16x8*)(Bt + (size_t)(n0 + r) * 512 + k0 + cc * 8);
    }
    __syncthreads();
    #pragma unroll
    for (int it = 0; it < 2; ++it) {
      int ch = it * 256 + tid;
      int r = ch >> 2, cc = ch & 3;
      *(u16x8*)(lA + r * 40 + cc * 8) = sa[it];
      *(u16x8*)(lB + r * 40 + cc * 8) = sb[it];
    }
    __syncthreads();
    bf16x8 af[4], bfv[4];
    #pragma unroll
    for (int mi = 0; mi < 4; ++mi)
      af[mi] = *(const bf16x8*)(lA + (wm + mi * 16 + c16) * 40 + quad * 8);
    #pragma unroll
    for (int ni = 0; ni < 4; ++ni)
      bfv[ni] = *(const bf16x8*)(lB + (wn + ni * 16 + c16) * 40 + quad * 8);
    #pragma unroll
    for (int mi = 0; mi < 4; ++mi)
      #pragma unroll
      for (int ni = 0; ni < 4; ++ni)
        acc[mi][ni] = __builtin_amdgcn_mfma_f32_16x16x32_bf16(af[mi], bfv[ni], acc[mi][ni], 0, 0, 0);
  }
  #pragma unroll
  for (int mi = 0; mi < 4; ++mi) {
    #pragma unroll
    for (int r = 0; r < 4; ++r) {
      int grow = row0 + wm + mi * 16 + quad * 4 + r;
      if (grow < BN) {
        #pragma unroll
        for (int ni = 0; ni < 4; ++ni) {
          int col = n0 + wn + ni * 16 + c16;
          out[(size_t)grow * 512 + col] = acc[mi][ni][r] + bout[col];
        }
      }
    }
  }
}

// ---------------- launch ----------------
extern "C" void kernel_launch(void* const* d_in, const int* in_sizes, int n_in,
                              void* d_out, int out_size, void* d_ws, size_t ws_size,
                              hipStream_t stream) {
  (void)in_sizes; (void)n_in; (void)out_size;
  if (ws_size < WS_NEEDED) return;   // fail clean, not crash
  const float* x    = (const float*)d_in[0];
  const float* Wqk  = (const float*)d_in[1];
  const float* Wv   = (const float*)d_in[2];
  const float* Wout = (const float*)d_in[3];
  const float* bout = (const float*)d_in[4];
  const float* relb = (const float*)d_in[5];
  const float* edel = (const float*)d_in[6];
  const float* ealp = (const float*)d_in[7];
  const float* ebet = (const float*)d_in[8];
  const float* egam = (const float*)d_in[9];
  const float* eome = (const float*)d_in[10];

  char* ws = (char*)d_ws;
  ushort* Wqkvt = (ushort*)(ws + OFF_WQKVT);
  ushort* Woutt = (ushort*)(ws + OFF_WOUTT);
  float*  qtab  = (float*)(ws + OFF_QTAB);
  float*  ctab  = (float*)(ws + OFF_CTAB);
  ushort* qkb   = (ushort*)(ws + OFF_QK);
  ushort* vb    = (ushort*)(ws + OFF_V);
  ushort* xm    = (ushort*)(ws + OFF_XM);
  ushort* vtb   = (ushort*)(ws + OFF_VT);
  ushort* aob   = (ushort*)(ws + OFF_AO);
  float*  outp  = (float*)d_out;
  float*  y1    = outp;                        // d_out as fp32 scratch
  float*  y2    = (float*)(ws + OFF_QK);       // QK region dead until k_qkv

  k_prep<<<dim3(4160), dim3(256), 0, stream>>>(edel, ealp, ebet, egam, Wqk, Wv, Wout,
                                               qtab, ctab, Wqkvt, Woutt);
  k_ema_scan<<<dim3(16, 32), dim3(64), 0, stream>>>(x, qtab, ctab, y1, y2);
  k_ema_comb<<<dim3(9232), dim3(256), 0, stream>>>(x, y1, y2, eome, xm);
  k_qkv<<<dim3(12, 145), dim3(256), 0, stream>>>(xm, Wqkvt, qkb, vb);
  k_vtrans<<<dim3(10, 256), dim3(256), 0, stream>>>(vb, vtb);
  k_fattn<<<dim3(256, 5), dim3(256), 0, stream>>>(qkb, vtb, relb, aob);
  k_out<<<dim3(4, 145), dim3(256), 0, stream>>>(aob, Woutt, bout, outp);
}

// Round 4
// 324.606 us; speedup vs baseline: 1.2715x; 1.0993x over previous
//
#include <hip/hip_runtime.h>

typedef unsigned short ushort;

typedef __bf16 bf16x8 __attribute__((ext_vector_type(8)));
typedef float  f32x4  __attribute__((ext_vector_type(4)));
typedef unsigned short u16x8 __attribute__((ext_vector_type(8)));
typedef unsigned short u16x4 __attribute__((ext_vector_type(4)));
typedef unsigned int   u32x2 __attribute__((ext_vector_type(2)));

static constexpr int BB   = 32;
static constexpr int NN   = 577;   // N = NP+1
static constexpr int LL   = 576;   // NP
static constexpr int DIMC = 512;
static constexpr int BN   = BB * NN;  // 18464

// ---------------- workspace arena (bytes), total 98,828,288 (~94.3 MB) -----
// y1 (fp32 EMA fwd) lives in d_out; y2 (fp32 EMA bwd) lives in the QK region
// (dead until k_qkv writes it). EMA chunk-states (16.8 MB) live in the AO
// region (dead until k_fattn writes it).
static constexpr size_t SZ_WQKVT = 1536ull * 512 * 2;
static constexpr size_t SZ_WOUTT = 512ull * 512 * 2;
static constexpr size_t SZ_QK    = (size_t)BN * 1024 * 2;    // 37,814,272
static constexpr size_t SZ_V     = (size_t)BN * 512 * 2;     // 18,907,136
static constexpr size_t SZ_VT    = 256ull * 64 * 640 * 2;    // 20,971,520
static constexpr size_t OFF_WQKVT = 0;
static constexpr size_t OFF_WOUTT = OFF_WQKVT + SZ_WQKVT;
static constexpr size_t OFF_QTAB  = OFF_WOUTT + SZ_WOUTT;
static constexpr size_t OFF_CTAB  = OFF_QTAB + 65536;
static constexpr size_t OFF_QK    = OFF_CTAB + 65536;
static constexpr size_t OFF_V     = OFF_QK + SZ_QK;
static constexpr size_t OFF_REGION= OFF_V + SZ_V;
static constexpr size_t OFF_XM    = OFF_REGION;              // xm dead after k_qkv
static constexpr size_t OFF_VT    = OFF_REGION;              // vt overlays xm
static constexpr size_t OFF_AO    = OFF_REGION + SZ_VT;
static constexpr size_t OFF_ST    = OFF_AO;                  // EMA states overlay ao
static constexpr size_t WS_NEEDED = OFF_AO + SZ_V;           // 98,828,288

// ---------------- helpers ----------------
__device__ __forceinline__ ushort bf16bits(float f) {
  unsigned int u = __builtin_bit_cast(unsigned int, f);
  u = (u + 0x7fffu + ((u >> 16) & 1u)) >> 16;
  return (ushort)u;
}
__device__ __forceinline__ float sigmoidf_(float z) { return 1.f / (1.f + __expf(-z)); }
__device__ __forceinline__ float siluf(float z)     { return z / (1.f + __expf(-z)); }

// ---------------- prep: EMA tables + bf16 transposed weights ----------------
__global__ __launch_bounds__(256) void k_prep(
    const float* __restrict__ delta, const float* __restrict__ alpha,
    const float* __restrict__ beta,  const float* __restrict__ gamma,
    const float* __restrict__ Wqk,   const float* __restrict__ Wv,
    const float* __restrict__ Wout,
    float* __restrict__ qtab, float* __restrict__ ctab,
    ushort* __restrict__ Wqkvt, ushort* __restrict__ Woutt)
{
  int idx = blockIdx.x * 256 + threadIdx.x;
  if (idx < 16384) {
    float p = sigmoidf_(delta[idx]);
    float q = 1.f - p * sigmoidf_(alpha[idx]);
    qtab[idx] = q;
    ctab[idx] = p * beta[idx] * gamma[idx] * 0.25f;   // scale = sqrt(1/16)
  }
  int i2 = idx - 16384;                                // Wqkv_t: [1536][512]
  if (i2 >= 0 && i2 < 1536 * 512) {
    int n = i2 >> 9, k = i2 & 511;
    float w = (n < 1024) ? Wqk[k * 1024 + n] : Wv[k * 512 + (n - 1024)];
    Wqkvt[i2] = bf16bits(w);
  }
  int i3 = i2 - 1536 * 512;                            // Wout_t: [512][512]
  if (i3 >= 0 && i3 < 512 * 512) {
    int n = i3 >> 9, k = i3 & 511;
    Woutt[i3] = bf16bits(Wout[k * 512 + n]);
  }
}

// ======== chunked EMA scan: h_t = q h_{t-1} + x_t is LINEAR, q in (0,1) ====
// 8 chunks of 72 steps. p1: per-chunk local end-state (h_in=0), chunks 0-6.
// mid: exclusive scan of states with q^72. p3: re-run each chunk seeded with
// the true h_init, compute y, store. Parallelism 512 -> 4096 waves (p3);
// round-3 rocprof: old monolithic scan was 4.9% occupancy, 85 us.
// st layout: [(dir*32+b)*8 + chunk][n(16)][d(512)] floats.

// ---- pass 1: chunk-local final states, chunks 0..6 each direction --------
__global__ __launch_bounds__(64) void k_ema_p1(
    const float* __restrict__ x, const float* __restrict__ qtab,
    float* __restrict__ st)
{
  const int gx = blockIdx.x, cy = blockIdx.y, b = blockIdx.z;
  if (gx < 8) {
    const int d = gx * 64 + threadIdx.x;
    float q[16], h[16];
    #pragma unroll
    for (int n = 0; n < 16; ++n) { q[n] = qtab[d*16+n]; h[n] = 0.f; }
    const float* xp = x + ((size_t)b * NN + 1) * DIMC + d;
    const int blo = cy * 9;
    float xn[8];
    #pragma unroll
    for (int u = 0; u < 8; ++u) xn[u] = xp[(blo * 8 + u) * DIMC];
    for (int blk = blo; blk < blo + 9; ++blk) {
      float xv[8];
      #pragma unroll
      for (int u = 0; u < 8; ++u) xv[u] = xn[u];
      if (blk < blo + 8) {
        #pragma unroll
        for (int u = 0; u < 8; ++u) xn[u] = xp[((blk + 1) * 8 + u) * DIMC];
      }
      #pragma unroll
      for (int u = 0; u < 8; ++u) {
        float xx = xv[u];
        #pragma unroll
        for (int n = 0; n < 16; ++n) h[n] = fmaf(q[n], h[n], xx);
      }
    }
    float* sp = st + (((size_t)b * 8 + cy) * 16) * 512 + d;
    #pragma unroll
    for (int n = 0; n < 16; ++n) sp[n * 512] = h[n];
  } else {
    const int d = (gx - 8) * 64 + threadIdx.x;
    float q[16], g[16];
    #pragma unroll
    for (int n = 0; n < 16; ++n) { q[n] = qtab[(d+512)*16+n]; g[n] = 0.f; }
    const float* xp = x + ((size_t)b * NN + 1) * DIMC + d;
    const int blo = (7 - cy) * 9;
    float xn[8];
    #pragma unroll
    for (int u = 0; u < 8; ++u) xn[u] = xp[((blo + 8) * 8 + u) * DIMC];
    for (int blk = blo + 8; blk >= blo; --blk) {
      float xv[8];
      #pragma unroll
      for (int u = 0; u < 8; ++u) xv[u] = xn[u];
      if (blk > blo) {
        #pragma unroll
        for (int u = 0; u < 8; ++u) xn[u] = xp[((blk - 1) * 8 + u) * DIMC];
      }
      #pragma unroll
      for (int u = 7; u >= 0; --u) {
        float xx = xv[u];
        #pragma unroll
        for (int n = 0; n < 16; ++n) g[n] = fmaf(q[n], g[n], xx);
      }
    }
    float* sp = st + (((size_t)(32 + b) * 8 + cy) * 16) * 512 + d;
    #pragma unroll
    for (int n = 0; n < 16; ++n) sp[n * 512] = g[n];
  }
}

// ---- mid: exclusive scan over chunk states with q^72 ----------------------
__global__ __launch_bounds__(256) void k_ema_mid(
    const float* __restrict__ qtab, float* __restrict__ st)
{
  int idx = blockIdx.x * 256 + threadIdx.x;   // 524,288 = 64*16*512
  int d = idx & 511;
  int rest = idx >> 9;          // db*16 + n
  int n = rest & 15;
  int db = rest >> 4;           // dir*32 + b
  int dir = db >> 5;
  float q = qtab[(((size_t)dir << 9) + d) * 16 + n];
  float q2 = q * q, q4 = q2 * q2, q8 = q4 * q4;
  float q16 = q8 * q8, q32 = q16 * q16, q64 = q32 * q32;
  float qL = q64 * q8;          // q^72
  float h = 0.f;
  float* sp = st + ((size_t)db * 128 + n) * 512 + d;
  #pragma unroll
  for (int c = 0; c < 8; ++c) {
    float tmp = (c < 7) ? sp[c * 8192] : 0.f;   // chunk stride 16*512
    sp[c * 8192] = h;
    h = fmaf(qL, h, tmp);
  }
}

// ---- pass 3: per-chunk scan with true h_init, y compute + store -----------
__global__ __launch_bounds__(64) void k_ema_p3(
    const float* __restrict__ x, const float* __restrict__ qtab,
    const float* __restrict__ ctab, const float* __restrict__ st,
    float* __restrict__ y1, float* __restrict__ y2)
{
  const int gx = blockIdx.x, cy = blockIdx.y, b = blockIdx.z;
  if (gx < 8) {
    const int d = gx * 64 + threadIdx.x;
    float q[16], c[16], h[16];
    const float* sp = st + (((size_t)b * 8 + cy) * 16) * 512 + d;
    #pragma unroll
    for (int n = 0; n < 16; ++n) { q[n] = qtab[d*16+n]; c[n] = ctab[d*16+n]; h[n] = sp[n*512]; }
    const float* xp = x  + ((size_t)b * NN + 1) * DIMC + d;
    float*       yp = y1 + ((size_t)b * LL)     * DIMC + d;
    const int blo = cy * 9;
    float xn[8];
    #pragma unroll
    for (int u = 0; u < 8; ++u) xn[u] = xp[(blo * 8 + u) * DIMC];
    for (int blk = blo; blk < blo + 9; ++blk) {
      float xv[8];
      #pragma unroll
      for (int u = 0; u < 8; ++u) xv[u] = xn[u];
      if (blk < blo + 8) {
        #pragma unroll
        for (int u = 0; u < 8; ++u) xn[u] = xp[((blk + 1) * 8 + u) * DIMC];
      }
      #pragma unroll
      for (int u = 0; u < 8; ++u) {
        float xx = xv[u], y = 0.f;
        #pragma unroll
        for (int n = 0; n < 16; ++n) { h[n] = fmaf(q[n], h[n], xx); y = fmaf(c[n], h[n], y); }
        yp[(blk * 8 + u) * DIMC] = y;
      }
    }
  } else {
    const int d = (gx - 8) * 64 + threadIdx.x;
    float q[16], c[16], g[16];
    const float* sp = st + (((size_t)(32 + b) * 8 + cy) * 16) * 512 + d;
    #pragma unroll
    for (int n = 0; n < 16; ++n) { q[n] = qtab[(d+512)*16+n]; c[n] = ctab[(d+512)*16+n]; g[n] = sp[n*512]; }
    const float* xp = x  + ((size_t)b * NN + 1) * DIMC + d;
    float*       yp = y2 + ((size_t)b * LL)     * DIMC + d;
    const int blo = (7 - cy) * 9;
    float xn[8];
    #pragma unroll
    for (int u = 0; u < 8; ++u) xn[u] = xp[((blo + 8) * 8 + u) * DIMC];
    for (int blk = blo + 8; blk >= blo; --blk) {
      float xv[8];
      #pragma unroll
      for (int u = 0; u < 8; ++u) xv[u] = xn[u];
      if (blk > blo) {
        #pragma unroll
        for (int u = 0; u < 8; ++u) xn[u] = xp[((blk - 1) * 8 + u) * DIMC];
      }
      #pragma unroll
      for (int u = 7; u >= 0; --u) {
        float xx = xv[u], y = 0.f;
        #pragma unroll
        for (int n = 0; n < 16; ++n) { g[n] = fmaf(q[n], g[n], xx); y = fmaf(c[n], g[n], y); }
        yp[(blk * 8 + u) * DIMC] = y;
      }
    }
  }
}

// -------- combine: xm = bf16(silu(y1+y2+x*omega)); cls row passthrough ------
__global__ __launch_bounds__(256) void k_ema_comb(
    const float* __restrict__ x, const float* __restrict__ y1,
    const float* __restrict__ y2, const float* __restrict__ omega,
    ushort* __restrict__ xm)
{
  size_t v = (size_t)blockIdx.x * 256 + threadIdx.x;   // vec4 index
  size_t e = v * 4;
  int n = (int)(e >> 9);
  int d = (int)(e & 511);
  int b = n / 577;
  int i = n - b * 577;
  f32x4 xv = *(const f32x4*)(x + e);
  u16x4 o;
  if (i == 0) {
    #pragma unroll
    for (int k = 0; k < 4; ++k) o[k] = bf16bits(xv[k]);
  } else {
    size_t ey = ((size_t)b * LL + (i - 1)) * DIMC + d;
    f32x4 a  = *(const f32x4*)(y1 + ey);
    f32x4 c2 = *(const f32x4*)(y2 + ey);
    f32x4 om = *(const f32x4*)(omega + d);
    #pragma unroll
    for (int k = 0; k < 4; ++k) o[k] = bf16bits(siluf(a[k] + c2[k] + xv[k] * om[k]));
  }
  *(u16x4*)(xm + e) = o;
}

// ---------------- QKV GEMM: xm[18464,512] @ Wqkv_t[1536,512]^T -------------
// q columns (n0<512) pre-scaled by 0.125 for attention. Rows padded 32->40
// ushorts (80 B) to stagger LDS banks (2-way, free).
// XCD-chunked block remap (bijective, nwg=1740): the 12 n-tiles sharing an
// A-row-panel are consecutive within one XCD chunk -> A panel stays in its L2.
__global__ __launch_bounds__(256) void k_qkv(
    const ushort* __restrict__ A, const ushort* __restrict__ Bt,
    ushort* __restrict__ qk, ushort* __restrict__ v)
{
  __shared__ alignas(16) ushort lA[128 * 40];
  __shared__ alignas(16) ushort lB[128 * 40];
  const int tid = threadIdx.x, wv = tid >> 6, lane = tid & 63;
  const int quad = lane >> 4, c16 = lane & 15;
  const int fid = blockIdx.y * 12 + blockIdx.x;        // dispatch-order id
  const int xcd = fid & 7, ord = fid >> 3;             // nwg=1740: q=217,r=4
  const int wg  = (xcd < 4 ? xcd * 218 : 872 + (xcd - 4) * 217) + ord;
  const int row0 = (wg / 12) * 128, n0 = (wg % 12) * 128;
  const int wm = (wv >> 1) * 64, wn = (wv & 1) * 64;
  f32x4 z4 = {0.f, 0.f, 0.f, 0.f};
  f32x4 acc[4][4];
  #pragma unroll
  for (int mi = 0; mi < 4; ++mi)
    #pragma unroll
    for (int ni = 0; ni < 4; ++ni) acc[mi][ni] = z4;

  for (int kt = 0; kt < 16; ++kt) {
    const int k0 = kt * 32;
    u16x8 sa[2], sb[2];
    #pragma unroll
    for (int it = 0; it < 2; ++it) {
      int ch = it * 256 + tid;
      int r = ch >> 2, cc = ch & 3;
      int grow = row0 + r; if (grow > BN - 1) grow = BN - 1;
      sa[it] = *(const u16x8*)(A + (size_t)grow * 512 + k0 + cc * 8);
      sb[it] = *(const u16x8*)(Bt + (size_t)(n0 + r) * 512 + k0 + cc * 8);
    }
    __syncthreads();
    #pragma unroll
    for (int it = 0; it < 2; ++it) {
      int ch = it * 256 + tid;
      int r = ch >> 2, cc = ch & 3;
      *(u16x8*)(lA + r * 40 + cc * 8) = sa[it];
      *(u16x8*)(lB + r * 40 + cc * 8) = sb[it];
    }
    __syncthreads();
    bf16x8 af[4], bfv[4];
    #pragma unroll
    for (int mi = 0; mi < 4; ++mi)
      af[mi] = *(const bf16x8*)(lA + (wm + mi * 16 + c16) * 40 + quad * 8);
    #pragma unroll
    for (int ni = 0; ni < 4; ++ni)
      bfv[ni] = *(const bf16x8*)(lB + (wn + ni * 16 + c16) * 40 + quad * 8);
    #pragma unroll
    for (int mi = 0; mi < 4; ++mi)
      #pragma unroll
      for (int ni = 0; ni < 4; ++ni)
        acc[mi][ni] = __builtin_amdgcn_mfma_f32_16x16x32_bf16(af[mi], bfv[ni], acc[mi][ni], 0, 0, 0);
  }
  const bool isv = (n0 >= 1024);
  const float osc = (n0 < 512) ? 0.125f : 1.0f;      // fold 1/sqrt(DH) into q
  #pragma unroll
  for (int mi = 0; mi < 4; ++mi) {
    #pragma unroll
    for (int r = 0; r < 4; ++r) {
      int grow = row0 + wm + mi * 16 + quad * 4 + r;
      if (grow < BN) {
        #pragma unroll
        for (int ni = 0; ni < 4; ++ni) {
          int col = n0 + wn + ni * 16 + c16;
          ushort vb = bf16bits(acc[mi][ni][r] * osc);
          if (!isv) qk[(size_t)grow * 1024 + col] = vb;
          else      v[(size_t)grow * 512 + (col - 1024)] = vb;
        }
      }
    }
  }
}

// ---------------- transpose v -> vt[bh*64+dh][640] (zero-padded j>=577) ----
__global__ __launch_bounds__(256) void k_vtrans(
    const ushort* __restrict__ v, ushort* __restrict__ vt)
{
  __shared__ alignas(16) ushort lt[64 * 72];
  const int tid = threadIdx.x;
  const int bh = blockIdx.y, b = bh >> 3, h = bh & 7;
  const int j0 = blockIdx.x * 64;
  #pragma unroll
  for (int pass = 0; pass < 2; ++pass) {
    int cch = pass * 256 + tid;
    int jl = cch >> 3, cc = cch & 7;
    int gj = j0 + jl;
    u16x8 val = {0, 0, 0, 0, 0, 0, 0, 0};
    if (gj < 577) val = *(const u16x8*)(v + ((size_t)(b * NN + gj)) * 512 + h * 64 + cc * 8);
    *(u16x8*)(lt + jl * 72 + cc * 8) = val;
  }
  __syncthreads();
  #pragma unroll
  for (int pass = 0; pass < 2; ++pass) {
    int cch = pass * 256 + tid;
    int dh = cch >> 3, jc = cch & 7;
    u16x8 o;
    #pragma unroll
    for (int e = 0; e < 8; ++e) o[e] = lt[(jc * 8 + e) * 72 + dh];
    *(u16x8*)(vt + ((size_t)(bh * 64 + dh)) * 640 + j0 + jc * 8) = o;
  }
}

// -------- fused flash attention: O = softmax(QK^T) V + Bias V --------------
// Static softmax (scores bounded ~|50| << 88 -> raw exp safe in fp32).
// Swapped QK^T (mfma(K,Q) -> S^T): a lane's 4 acc values are 4 CONSECUTIVE
// P columns of one row -> RNE bit-pack (bf16bits, NOT v_cvt_pk_bf16_f32:
// the asm cvt rounds differently -> absmax 0.0078 -> 0.0406, round-2 fail)
// + single 8-byte LDS write (replaces 32 scalar u16 writes per tile).
// Q lives in registers (lq LDS dropped: 50.5->34.5 KB). No min-waves cap:
// launch_bounds(256,4) forced 128-reg budget -> accumulator spills (round 1:
// WRITE_SIZE 18->126 MB, dur 92->135 us). Allocator takes ~150 VGPRs.
// Next K/V tile loads issue at PV start: latency hides under PV, drained at
// next loop-top barrier.
// Grid (bh, itile): 256 % 8 == 0 -> all 5 i-tiles of a bh land on one XCD
// (K/V tiles stay in that XCD's L2).
__global__ __launch_bounds__(256) void k_fattn(
    const ushort* __restrict__ qk, const ushort* __restrict__ vt,
    const float* __restrict__ relb, ushort* __restrict__ ao)
{
  __shared__ alignas(16) ushort lk[64 * 64];
  __shared__ alignas(16) ushort lv[64 * 64];
  __shared__ alignas(16) ushort lp[128 * 64];
  __shared__ ushort lbias16[1280];     // bf16 bias at +64 offset, pad-safe
  const int tid = threadIdx.x, wv = tid >> 6, lane = tid & 63;
  const int quad = lane >> 4, c16 = lane & 15;
  const int bh = blockIdx.x, b = bh >> 3, h = bh & 7;
  const int i0 = blockIdx.y * 128, wm = wv * 32;
  for (int t = tid; t < 1280; t += 256) {
    int idx = t - 64;
    lbias16[t] = (idx >= 0 && idx < 1153) ? bf16bits(relb[idx]) : (ushort)0;
  }
  // Q fragments in registers for the whole block (rows wm+ms*16+c16)
  bf16x8 aq[2][2];
  #pragma unroll
  for (int ms = 0; ms < 2; ++ms) {
    int gi = i0 + wm + ms * 16 + c16; if (gi > 576) gi = 576;
    const ushort* qp = qk + ((size_t)(b * NN + gi)) * 1024 + h * 64;
    #pragma unroll
    for (int kk = 0; kk < 2; ++kk)
      aq[ms][kk] = *(const bf16x8*)(qp + (kk * 4 + quad) * 8);
  }
  const int s_r = tid >> 3, s_c = tid & 7;
  const ushort* kbase = qk + ((size_t)b * NN) * 1024 + 512 + h * 64 + s_c * 8;
  const ushort* vbase = vt + ((size_t)bh * 64) * 640 + s_c * 8;

  float lsum[2] = {0.f, 0.f};
  f32x4 z4 = {0.f, 0.f, 0.f, 0.f};
  f32x4 accp[2][4], accb[2][4];
  #pragma unroll
  for (int ms = 0; ms < 2; ++ms)
    #pragma unroll
    for (int ns = 0; ns < 4; ++ns) { accp[ms][ns] = z4; accb[ms][ns] = z4; }

  // preload tile jt=0 (j = 0..63, no clamp needed)
  u16x8 sk[2], sv[2];
  #pragma unroll
  for (int it = 0; it < 2; ++it) {
    int r = it * 32 + s_r;
    sk[it] = *(const u16x8*)(kbase + (size_t)r * 1024);
    sv[it] = *(const u16x8*)(vbase + (size_t)r * 640);
  }

  for (int jt = 0; jt < 10; ++jt) {
    __syncthreads();                       // prior lk/lv/lp readers done (+ drains prefetch)
    #pragma unroll
    for (int it = 0; it < 2; ++it) {
      int r = it * 32 + s_r;
      int pc = (s_c ^ (r & 7)) * 8;
      *(u16x8*)(lk + r * 64 + pc) = sk[it];
      *(u16x8*)(lv + r * 64 + pc) = sv[it];
    }
    __syncthreads();                       // staging visible
    // ---- S^T = K Q^T, one ms (16 q-rows) at a time; softmax fused per ms
    #pragma unroll
    for (int ms = 0; ms < 2; ++ms) {
      f32x4 dacc[4] = {z4, z4, z4, z4};
      #pragma unroll
      for (int kk = 0; kk < 2; ++kk) {
        const int ck = kk * 4 + quad;
        #pragma unroll
        for (int ns = 0; ns < 4; ++ns) {
          const int row = ns * 16 + c16;
          bf16x8 bk = *(const bf16x8*)(lk + row * 64 + ((ck ^ (row & 7)) * 8));
          dacc[ns] = __builtin_amdgcn_mfma_f32_16x16x32_bf16(bk, aq[ms][kk], dacc[ns], 0, 0, 0);
        }
      }
      // lane holds S[i = wm+ms*16+c16][j = j0 + ns*16 + quad*4 + r]
      const int irow = wm + ms * 16 + c16;
      const int xr = irow & 7;
      #pragma unroll
      for (int ns = 0; ns < 4; ++ns) {
        float ex[4];
        #pragma unroll
        for (int r = 0; r < 4; ++r) {
          float e = __expf(dacc[ns][r]);
          if (jt == 9 && (ns * 16 + quad * 4 + r) >= 1) e = 0.f;   // j >= 577
          ex[r] = e;
        }
        lsum[ms] += (ex[0] + ex[1]) + (ex[2] + ex[3]);
        unsigned int p0 = (unsigned int)bf16bits(ex[0]) | ((unsigned int)bf16bits(ex[1]) << 16);
        unsigned int p1 = (unsigned int)bf16bits(ex[2]) | ((unsigned int)bf16bits(ex[3]) << 16);
        u32x2 pw = {p0, p1};
        const int lc = ns * 2 + (quad >> 1);         // logical 8-col chunk
        *(u32x2*)(lp + irow * 64 + ((lc ^ xr) * 8) + (quad & 1) * 4) = pw;
      }
    }
    __syncthreads();                       // lp visible
    // issue next K/V tile loads now: latency hides under PV below
    if (jt < 9) {
      const int j0n = (jt + 1) * 64;
      #pragma unroll
      for (int it = 0; it < 2; ++it) {
        int r = it * 32 + s_r;
        int gj = j0n + r; if (gj > 576) gj = 576;
        sk[it] = *(const u16x8*)(kbase + (size_t)gj * 1024);
        sv[it] = *(const u16x8*)(vbase + (size_t)r * 640 + j0n);
      }
    }
    // ---- O += P~ V  and  O_b += Bias V
    const int j0 = jt * 64;
    #pragma unroll
    for (int kk = 0; kk < 2; ++kk) {
      const int ck = kk * 4 + quad;
      bf16x8 ap[2], ab[2];
      #pragma unroll
      for (int ms = 0; ms < 2; ++ms) {
        const int row = wm + ms * 16 + c16;
        ap[ms] = *(const bf16x8*)(lp + row * 64 + ((ck ^ (row & 7)) * 8));
        u16x8 abu;
        const int base = 64 + 576 + j0 + kk * 32 + quad * 8 - (i0 + row);
        #pragma unroll
        for (int e = 0; e < 8; ++e) abu[e] = lbias16[base + e];
        ab[ms] = __builtin_bit_cast(bf16x8, abu);
      }
      #pragma unroll
      for (int ns = 0; ns < 4; ++ns) {
        const int row = ns * 16 + c16;
        bf16x8 bV = *(const bf16x8*)(lv + row * 64 + ((ck ^ (row & 7)) * 8));
        #pragma unroll
        for (int ms = 0; ms < 2; ++ms) {
          accp[ms][ns] = __builtin_amdgcn_mfma_f32_16x16x32_bf16(ap[ms], bV, accp[ms][ns], 0, 0, 0);
          accb[ms][ns] = __builtin_amdgcn_mfma_f32_16x16x32_bf16(ab[ms], bV, accb[ms][ns], 0, 0, 0);
        }
      }
    }
  }
  // ---- epilogue: row sums live per-lane for row c16; reduce across quads,
  // then shfl the needed row's total (rows quad*4+r of the output C-layout).
  float tot[2];
  #pragma unroll
  for (int ms = 0; ms < 2; ++ms) {
    float t = lsum[ms];
    t += __shfl_xor(t, 16);
    t += __shfl_xor(t, 32);
    tot[ms] = t;
  }
  #pragma unroll
  for (int ms = 0; ms < 2; ++ms) {
    #pragma unroll
    for (int r = 0; r < 4; ++r) {
      float li = 1.f / __shfl(tot[ms], quad * 4 + r);
      int ii = i0 + wm + ms * 16 + quad * 4 + r;
      if (ii < 577) {
        #pragma unroll
        for (int ns = 0; ns < 4; ++ns)
          ao[((size_t)(b * NN + ii)) * 512 + h * 64 + ns * 16 + c16] =
              bf16bits(accp[ms][ns][r] * li + accb[ms][ns][r]);
      }
    }
  }
}

// ---------------- out GEMM: ao[18464,512] @ Wout_t[512,512]^T + b_out -----
__global__ __launch_bounds__(256) void k_out(
    const ushort* __restrict__ A, const ushort* __restrict__ Bt,
    const float* __restrict__ bout, float* __restrict__ out)
{
  __shared__ alignas(16) ushort lA[128 * 40];
  __shared__ alignas(16) ushort lB[128 * 40];
  const int tid = threadIdx.x, wv = tid >> 6, lane = tid & 63;
  const int quad = lane >> 4, c16 = lane & 15;
  const int row0 = blockIdx.y * 128, n0 = blockIdx.x * 128;
  const int wm = (wv >> 1) * 64, wn = (wv & 1) * 64;
  f32x4 z4 = {0.f, 0.f, 0.f, 0.f};
  f32x4 acc[4][4];
  #pragma unroll
  for (int mi = 0; mi < 4; ++mi)
    #pragma unroll
    for (int ni = 0; ni < 4; ++ni) acc[mi][ni] = z4;

  for (int kt = 0; kt < 16; ++kt) {
    const int k0 = kt * 32;
    u16x8 sa[2], sb[2];
    #pragma unroll
    for (int it = 0; it < 2; ++it) {
      int ch = it * 256 + tid;
      int r = ch >> 2, cc = ch & 3;
      int grow = row0 + r; if (grow > BN - 1) grow = BN - 1;
      sa[it] = *(const u16x8*)(A + (size_t)grow * 512 + k0 + cc * 8);
      sb[it] = *(const u16x8*)(Bt + (size_t)(n0 + r) * 512 + k0 + cc * 8);
    }
    __syncthreads();
    #pragma unroll
    for (int it = 0; it < 2; ++it) {
      int ch = it * 256 + tid;
      int r = ch >> 2, cc = ch & 3;
      *(u16x8*)(lA + r * 40 + cc * 8) = sa[it];
      *(u16x8*)(lB + r * 40 + cc * 8) = sb[it];
    }
    __syncthreads();
    bf16x8 af[4], bfv[4];
    #pragma unroll
    for (int mi = 0; mi < 4; ++mi)
      af[mi] = *(const bf16x8*)(lA + (wm + mi * 16 + c16) * 40 + quad * 8);
    #pragma unroll
    for (int ni = 0; ni < 4; ++ni)
      bfv[ni] = *(const bf16x8*)(lB + (wn + ni * 16 + c16) * 40 + quad * 8);
    #pragma unroll
    for (int mi = 0; mi < 4; ++mi)
      #pragma unroll
      for (int ni = 0; ni < 4; ++ni)
        acc[mi][ni] = __builtin_amdgcn_mfma_f32_16x16x32_bf16(af[mi], bfv[ni], acc[mi][ni], 0, 0, 0);
  }
  #pragma unroll
  for (int mi = 0; mi < 4; ++mi) {
    #pragma unroll
    for (int r = 0; r < 4; ++r) {
      int grow = row0 + wm + mi * 16 + quad * 4 + r;
      if (grow < BN) {
        #pragma unroll
        for (int ni = 0; ni < 4; ++ni) {
          int col = n0 + wn + ni * 16 + c16;
          out[(size_t)grow * 512 + col] = acc[mi][ni][r] + bout[col];
        }
      }
    }
  }
}

// ---------------- launch ----------------
extern "C" void kernel_launch(void* const* d_in, const int* in_sizes, int n_in,
                              void* d_out, int out_size, void* d_ws, size_t ws_size,
                              hipStream_t stream) {
  (void)in_sizes; (void)n_in; (void)out_size;
  if (ws_size < WS_NEEDED) return;   // fail clean, not crash
  const float* x    = (const float*)d_in[0];
  const float* Wqk  = (const float*)d_in[1];
  const float* Wv   = (const float*)d_in[2];
  const float* Wout = (const float*)d_in[3];
  const float* bout = (const float*)d_in[4];
  const float* relb = (const float*)d_in[5];
  const float* edel = (const float*)d_in[6];
  const float* ealp = (const float*)d_in[7];
  const float* ebet = (const float*)d_in[8];
  const float* egam = (const float*)d_in[9];
  const float* eome = (const float*)d_in[10];

  char* ws = (char*)d_ws;
  ushort* Wqkvt = (ushort*)(ws + OFF_WQKVT);
  ushort* Woutt = (ushort*)(ws + OFF_WOUTT);
  float*  qtab  = (float*)(ws + OFF_QTAB);
  float*  ctab  = (float*)(ws + OFF_CTAB);
  ushort* qkb   = (ushort*)(ws + OFF_QK);
  ushort* vb    = (ushort*)(ws + OFF_V);
  ushort* xm    = (ushort*)(ws + OFF_XM);
  ushort* vtb   = (ushort*)(ws + OFF_VT);
  ushort* aob   = (ushort*)(ws + OFF_AO);
  float*  stf   = (float*)(ws + OFF_ST);       // EMA chunk states (dead before fattn)
  float*  outp  = (float*)d_out;
  float*  y1    = outp;                        // d_out as fp32 scratch
  float*  y2    = (float*)(ws + OFF_QK);       // QK region dead until k_qkv

  k_prep<<<dim3(4160), dim3(256), 0, stream>>>(edel, ealp, ebet, egam, Wqk, Wv, Wout,
                                               qtab, ctab, Wqkvt, Woutt);
  k_ema_p1<<<dim3(16, 7, 32), dim3(64), 0, stream>>>(x, qtab, stf);
  k_ema_mid<<<dim3(2048), dim3(256), 0, stream>>>(qtab, stf);
  k_ema_p3<<<dim3(16, 8, 32), dim3(64), 0, stream>>>(x, qtab, ctab, stf, y1, y2);
  k_ema_comb<<<dim3(9232), dim3(256), 0, stream>>>(x, y1, y2, eome, xm);
  k_qkv<<<dim3(12, 145), dim3(256), 0, stream>>>(xm, Wqkvt, qkb, vb);
  k_vtrans<<<dim3(10, 256), dim3(256), 0, stream>>>(vb, vtb);
  k_fattn<<<dim3(256, 5), dim3(256), 0, stream>>>(qkb, vtb, relb, aob);
  k_out<<<dim3(4, 145), dim3(256), 0, stream>>>(aob, Woutt, bout, outp);
}

// Round 5
// 306.429 us; speedup vs baseline: 1.3469x; 1.0593x over previous
//
#include <hip/hip_runtime.h>

typedef unsigned short ushort;

typedef __bf16 bf16x8 __attribute__((ext_vector_type(8)));
typedef float  f32x4  __attribute__((ext_vector_type(4)));
typedef unsigned short u16x8 __attribute__((ext_vector_type(8)));
typedef unsigned short u16x4 __attribute__((ext_vector_type(4)));
typedef unsigned int   u32x2 __attribute__((ext_vector_type(2)));

static constexpr int BB   = 32;
static constexpr int NN   = 577;   // N = NP+1
static constexpr int LL   = 576;   // NP
static constexpr int DIMC = 512;
static constexpr int BN   = BB * NN;  // 18464

// ---------------- workspace arena (bytes), total 98,828,288 (~94.3 MB) -----
// EMA chunk-states (16.8 MB) live in the AO region (dead until k_fattn).
static constexpr size_t SZ_WQKVT = 1536ull * 512 * 2;
static constexpr size_t SZ_WOUTT = 512ull * 512 * 2;
static constexpr size_t SZ_QK    = (size_t)BN * 1024 * 2;    // 37,814,272
static constexpr size_t SZ_V     = (size_t)BN * 512 * 2;     // 18,907,136
static constexpr size_t SZ_VT    = 256ull * 64 * 640 * 2;    // 20,971,520
static constexpr size_t OFF_WQKVT = 0;
static constexpr size_t OFF_WOUTT = OFF_WQKVT + SZ_WQKVT;
static constexpr size_t OFF_QTAB  = OFF_WOUTT + SZ_WOUTT;
static constexpr size_t OFF_CTAB  = OFF_QTAB + 65536;
static constexpr size_t OFF_QK    = OFF_CTAB + 65536;
static constexpr size_t OFF_V     = OFF_QK + SZ_QK;
static constexpr size_t OFF_REGION= OFF_V + SZ_V;
static constexpr size_t OFF_XM    = OFF_REGION;              // xm dead after k_qkv
static constexpr size_t OFF_VT    = OFF_REGION;              // vt overlays xm
static constexpr size_t OFF_AO    = OFF_REGION + SZ_VT;
static constexpr size_t OFF_ST    = OFF_AO;                  // EMA states overlay ao
static constexpr size_t WS_NEEDED = OFF_AO + SZ_V;           // 98,828,288

// ---------------- helpers ----------------
__device__ __forceinline__ ushort bf16bits(float f) {
  unsigned int u = __builtin_bit_cast(unsigned int, f);
  u = (u + 0x7fffu + ((u >> 16) & 1u)) >> 16;
  return (ushort)u;
}
__device__ __forceinline__ float sigmoidf_(float z) { return 1.f / (1.f + __expf(-z)); }
__device__ __forceinline__ float siluf(float z)     { return z / (1.f + __expf(-z)); }

// ---------------- prep: EMA tables + bf16 transposed weights ----------------
__global__ __launch_bounds__(256) void k_prep(
    const float* __restrict__ delta, const float* __restrict__ alpha,
    const float* __restrict__ beta,  const float* __restrict__ gamma,
    const float* __restrict__ Wqk,   const float* __restrict__ Wv,
    const float* __restrict__ Wout,
    float* __restrict__ qtab, float* __restrict__ ctab,
    ushort* __restrict__ Wqkvt, ushort* __restrict__ Woutt)
{
  int idx = blockIdx.x * 256 + threadIdx.x;
  if (idx < 16384) {
    float p = sigmoidf_(delta[idx]);
    float q = 1.f - p * sigmoidf_(alpha[idx]);
    qtab[idx] = q;
    ctab[idx] = p * beta[idx] * gamma[idx] * 0.25f;   // scale = sqrt(1/16)
  }
  int i2 = idx - 16384;                                // Wqkv_t: [1536][512]
  if (i2 >= 0 && i2 < 1536 * 512) {
    int n = i2 >> 9, k = i2 & 511;
    float w = (n < 1024) ? Wqk[k * 1024 + n] : Wv[k * 512 + (n - 1024)];
    Wqkvt[i2] = bf16bits(w);
  }
  int i3 = i2 - 1536 * 512;                            // Wout_t: [512][512]
  if (i3 >= 0 && i3 < 512 * 512) {
    int n = i3 >> 9, k = i3 & 511;
    Woutt[i3] = bf16bits(Wout[k * 512 + n]);
  }
}

// ======== chunked EMA scan: h_t = q h_{t-1} + x_t is LINEAR, q in (0,1) ====
// 8 chunks of 72 steps. p1: per-chunk local end-state (h_in=0), chunks 0-6
// per direction. mid: exclusive scan of states with q^72. fuse: one block
// per (d-group, row-chunk, b) runs the BACKWARD pass (y2 -> fp16 LDS), then
// the FORWARD pass, combining y1+y2+x*omega, silu, bf16 -> xm directly.
// Kills k_ema_comb and the 150 MB y1/y2 HBM round-trip of round 4.
// st layout: [(dir*32+b)*8 + chunk][n(16)][d(512)] floats.

// ---- pass 1: chunk-local final states, chunks 0..6 each direction --------
__global__ __launch_bounds__(64) void k_ema_p1(
    const float* __restrict__ x, const float* __restrict__ qtab,
    float* __restrict__ st)
{
  const int gx = blockIdx.x, cy = blockIdx.y, b = blockIdx.z;
  if (gx < 8) {
    const int d = gx * 64 + threadIdx.x;
    float q[16], h[16];
    #pragma unroll
    for (int n = 0; n < 16; ++n) { q[n] = qtab[d*16+n]; h[n] = 0.f; }
    const float* xp = x + ((size_t)b * NN + 1) * DIMC + d;
    const int blo = cy * 9;
    float xn[8];
    #pragma unroll
    for (int u = 0; u < 8; ++u) xn[u] = xp[(blo * 8 + u) * DIMC];
    for (int blk = blo; blk < blo + 9; ++blk) {
      float xv[8];
      #pragma unroll
      for (int u = 0; u < 8; ++u) xv[u] = xn[u];
      if (blk < blo + 8) {
        #pragma unroll
        for (int u = 0; u < 8; ++u) xn[u] = xp[((blk + 1) * 8 + u) * DIMC];
      }
      #pragma unroll
      for (int u = 0; u < 8; ++u) {
        float xx = xv[u];
        #pragma unroll
        for (int n = 0; n < 16; ++n) h[n] = fmaf(q[n], h[n], xx);
      }
    }
    float* sp = st + (((size_t)b * 8 + cy) * 16) * 512 + d;
    #pragma unroll
    for (int n = 0; n < 16; ++n) sp[n * 512] = h[n];
  } else {
    const int d = (gx - 8) * 64 + threadIdx.x;
    float q[16], g[16];
    #pragma unroll
    for (int n = 0; n < 16; ++n) { q[n] = qtab[(d+512)*16+n]; g[n] = 0.f; }
    const float* xp = x + ((size_t)b * NN + 1) * DIMC + d;
    const int blo = (7 - cy) * 9;
    float xn[8];
    #pragma unroll
    for (int u = 0; u < 8; ++u) xn[u] = xp[((blo + 8) * 8 + u) * DIMC];
    for (int blk = blo + 8; blk >= blo; --blk) {
      float xv[8];
      #pragma unroll
      for (int u = 0; u < 8; ++u) xv[u] = xn[u];
      if (blk > blo) {
        #pragma unroll
        for (int u = 0; u < 8; ++u) xn[u] = xp[((blk - 1) * 8 + u) * DIMC];
      }
      #pragma unroll
      for (int u = 7; u >= 0; --u) {
        float xx = xv[u];
        #pragma unroll
        for (int n = 0; n < 16; ++n) g[n] = fmaf(q[n], g[n], xx);
      }
    }
    float* sp = st + (((size_t)(32 + b) * 8 + cy) * 16) * 512 + d;
    #pragma unroll
    for (int n = 0; n < 16; ++n) sp[n * 512] = g[n];
  }
}

// ---- mid: exclusive scan over chunk states with q^72 ----------------------
__global__ __launch_bounds__(256) void k_ema_mid(
    const float* __restrict__ qtab, float* __restrict__ st)
{
  int idx = blockIdx.x * 256 + threadIdx.x;   // 524,288 = 64*16*512
  int d = idx & 511;
  int rest = idx >> 9;          // db*16 + n
  int n = rest & 15;
  int db = rest >> 4;           // dir*32 + b
  int dir = db >> 5;
  float q = qtab[(((size_t)dir << 9) + d) * 16 + n];
  float q2 = q * q, q4 = q2 * q2, q8 = q4 * q4;
  float q16 = q8 * q8, q32 = q16 * q16, q64 = q32 * q32;
  float qL = q64 * q8;          // q^72
  float h = 0.f;
  float* sp = st + ((size_t)db * 128 + n) * 512 + d;
  #pragma unroll
  for (int c = 0; c < 8; ++c) {
    float tmp = (c < 7) ? sp[c * 8192] : 0.f;   // chunk stride 16*512
    sp[c * 8192] = h;
    h = fmaf(qL, h, tmp);
  }
}

// ---- fused pass 3: bwd (y2->LDS fp16) then fwd + combine + silu -> xm -----
// One block = one (64-wide d-group, 72-row chunk, b). Bwd chunk index for
// row-chunk cy is (7-cy). cls row (i=0) written by cy==0 blocks.
__global__ __launch_bounds__(64) void k_ema_fuse(
    const float* __restrict__ x, const float* __restrict__ qtab,
    const float* __restrict__ ctab, const float* __restrict__ st,
    const float* __restrict__ omega, ushort* __restrict__ xm)
{
  __shared__ _Float16 yb[72 * 64];   // 9,216 B -> 16 blocks/CU
  const int lane = threadIdx.x;
  const int gx = blockIdx.x, cy = blockIdx.y, b = blockIdx.z;
  const int d = gx * 64 + lane;
  const float* xp = x + ((size_t)b * NN + 1 + cy * 72) * DIMC + d;
  { // backward pass over this chunk's 72 rows
    float q[16], c[16], g[16];
    const float* sp = st + (((size_t)(32 + b) * 8 + (7 - cy)) * 16) * 512 + d;
    #pragma unroll
    for (int n = 0; n < 16; ++n) {
      q[n] = qtab[(d + 512) * 16 + n];
      c[n] = ctab[(d + 512) * 16 + n];
      g[n] = sp[n * 512];
    }
    float xn[8];
    #pragma unroll
    for (int u = 0; u < 8; ++u) xn[u] = xp[(64 + u) * DIMC];
    for (int blk = 8; blk >= 0; --blk) {
      float xv[8];
      #pragma unroll
      for (int u = 0; u < 8; ++u) xv[u] = xn[u];
      if (blk > 0) {
        #pragma unroll
        for (int u = 0; u < 8; ++u) xn[u] = xp[((blk - 1) * 8 + u) * DIMC];
      }
      #pragma unroll
      for (int u = 7; u >= 0; --u) {
        float xx = xv[u], y = 0.f;
        #pragma unroll
        for (int n = 0; n < 16; ++n) { g[n] = fmaf(q[n], g[n], xx); y = fmaf(c[n], g[n], y); }
        yb[(blk * 8 + u) * 64 + lane] = (_Float16)y;
      }
    }
  }
  __syncthreads();
  { // forward pass + combine
    float q[16], c[16], h[16];
    const float* sp = st + (((size_t)b * 8 + cy) * 16) * 512 + d;
    #pragma unroll
    for (int n = 0; n < 16; ++n) {
      q[n] = qtab[d * 16 + n];
      c[n] = ctab[d * 16 + n];
      h[n] = sp[n * 512];
    }
    const float om = omega[d];
    ushort* op = xm + ((size_t)b * NN + 1 + cy * 72) * DIMC + d;
    float xn[8];
    #pragma unroll
    for (int u = 0; u < 8; ++u) xn[u] = xp[u * DIMC];
    for (int blk = 0; blk < 9; ++blk) {
      float xv[8];
      #pragma unroll
      for (int u = 0; u < 8; ++u) xv[u] = xn[u];
      if (blk < 8) {
        #pragma unroll
        for (int u = 0; u < 8; ++u) xn[u] = xp[((blk + 1) * 8 + u) * DIMC];
      }
      #pragma unroll
      for (int u = 0; u < 8; ++u) {
        float xx = xv[u], y = 0.f;
        #pragma unroll
        for (int n = 0; n < 16; ++n) { h[n] = fmaf(q[n], h[n], xx); y = fmaf(c[n], h[n], y); }
        float s = y + (float)yb[(blk * 8 + u) * 64 + lane] + xx * om;
        op[(blk * 8 + u) * DIMC] = bf16bits(siluf(s));
      }
    }
  }
  if (cy == 0) {   // cls row passthrough
    size_t e0 = ((size_t)b * NN) * DIMC + d;
    xm[e0] = bf16bits(x[e0]);
  }
}

// ---------------- QKV GEMM: xm[18464,512] @ Wqkv_t[1536,512]^T -------------
// q columns (n0<512) pre-scaled by 0.125*log2(e): folds both 1/sqrt(DH) and
// the exp->exp2 conversion into Q so k_fattn uses raw v_exp_f32.
// Rows padded 32->40 ushorts (80 B) to stagger LDS banks (2-way, free).
// XCD-chunked block remap (bijective, nwg=1740).
__global__ __launch_bounds__(256) void k_qkv(
    const ushort* __restrict__ A, const ushort* __restrict__ Bt,
    ushort* __restrict__ qk, ushort* __restrict__ v)
{
  __shared__ alignas(16) ushort lA[128 * 40];
  __shared__ alignas(16) ushort lB[128 * 40];
  const int tid = threadIdx.x, wv = tid >> 6, lane = tid & 63;
  const int quad = lane >> 4, c16 = lane & 15;
  const int fid = blockIdx.y * 12 + blockIdx.x;        // dispatch-order id
  const int xcd = fid & 7, ord = fid >> 3;             // nwg=1740: q=217,r=4
  const int wg  = (xcd < 4 ? xcd * 218 : 872 + (xcd - 4) * 217) + ord;
  const int row0 = (wg / 12) * 128, n0 = (wg % 12) * 128;
  const int wm = (wv >> 1) * 64, wn = (wv & 1) * 64;
  f32x4 z4 = {0.f, 0.f, 0.f, 0.f};
  f32x4 acc[4][4];
  #pragma unroll
  for (int mi = 0; mi < 4; ++mi)
    #pragma unroll
    for (int ni = 0; ni < 4; ++ni) acc[mi][ni] = z4;

  for (int kt = 0; kt < 16; ++kt) {
    const int k0 = kt * 32;
    u16x8 sa[2], sb[2];
    #pragma unroll
    for (int it = 0; it < 2; ++it) {
      int ch = it * 256 + tid;
      int r = ch >> 2, cc = ch & 3;
      int grow = row0 + r; if (grow > BN - 1) grow = BN - 1;
      sa[it] = *(const u16x8*)(A + (size_t)grow * 512 + k0 + cc * 8);
      sb[it] = *(const u16x8*)(Bt + (size_t)(n0 + r) * 512 + k0 + cc * 8);
    }
    __syncthreads();
    #pragma unroll
    for (int it = 0; it < 2; ++it) {
      int ch = it * 256 + tid;
      int r = ch >> 2, cc = ch & 3;
      *(u16x8*)(lA + r * 40 + cc * 8) = sa[it];
      *(u16x8*)(lB + r * 40 + cc * 8) = sb[it];
    }
    __syncthreads();
    bf16x8 af[4], bfv[4];
    #pragma unroll
    for (int mi = 0; mi < 4; ++mi)
      af[mi] = *(const bf16x8*)(lA + (wm + mi * 16 + c16) * 40 + quad * 8);
    #pragma unroll
    for (int ni = 0; ni < 4; ++ni)
      bfv[ni] = *(const bf16x8*)(lB + (wn + ni * 16 + c16) * 40 + quad * 8);
    #pragma unroll
    for (int mi = 0; mi < 4; ++mi)
      #pragma unroll
      for (int ni = 0; ni < 4; ++ni)
        acc[mi][ni] = __builtin_amdgcn_mfma_f32_16x16x32_bf16(af[mi], bfv[ni], acc[mi][ni], 0, 0, 0);
  }
  const bool isv = (n0 >= 1024);
  const float osc = (n0 < 512) ? 0.1803368801111f : 1.0f;  // 0.125*log2(e)
  #pragma unroll
  for (int mi = 0; mi < 4; ++mi) {
    #pragma unroll
    for (int r = 0; r < 4; ++r) {
      int grow = row0 + wm + mi * 16 + quad * 4 + r;
      if (grow < BN) {
        #pragma unroll
        for (int ni = 0; ni < 4; ++ni) {
          int col = n0 + wn + ni * 16 + c16;
          ushort vb = bf16bits(acc[mi][ni][r] * osc);
          if (!isv) qk[(size_t)grow * 1024 + col] = vb;
          else      v[(size_t)grow * 512 + (col - 1024)] = vb;
        }
      }
    }
  }
}

// ---------------- transpose v -> vt[bh*64+dh][640] (zero-padded j>=577) ----
__global__ __launch_bounds__(256) void k_vtrans(
    const ushort* __restrict__ v, ushort* __restrict__ vt)
{
  __shared__ alignas(16) ushort lt[64 * 72];
  const int tid = threadIdx.x;
  const int bh = blockIdx.y, b = bh >> 3, h = bh & 7;
  const int j0 = blockIdx.x * 64;
  #pragma unroll
  for (int pass = 0; pass < 2; ++pass) {
    int cch = pass * 256 + tid;
    int jl = cch >> 3, cc = cch & 7;
    int gj = j0 + jl;
    u16x8 val = {0, 0, 0, 0, 0, 0, 0, 0};
    if (gj < 577) val = *(const u16x8*)(v + ((size_t)(b * NN + gj)) * 512 + h * 64 + cc * 8);
    *(u16x8*)(lt + jl * 72 + cc * 8) = val;
  }
  __syncthreads();
  #pragma unroll
  for (int pass = 0; pass < 2; ++pass) {
    int cch = pass * 256 + tid;
    int dh = cch >> 3, jc = cch & 7;
    u16x8 o;
    #pragma unroll
    for (int e = 0; e < 8; ++e) o[e] = lt[(jc * 8 + e) * 72 + dh];
    *(u16x8*)(vt + ((size_t)(bh * 64 + dh)) * 640 + j0 + jc * 8) = o;
  }
}

// -------- fused flash attention: O = softmax(QK^T) V + Bias V --------------
// Static softmax; Q pre-scaled by 0.125*log2(e) -> raw exp2 (single
// v_exp_f32, no mul). Swapped QK^T (mfma(K,Q) -> S^T) + RNE bit-pack +
// 8-byte lp writes. 2 barriers/tile (lp barrier removed: each wave reads
// ONLY its own lp rows [wm,wm+32), in-wave lgkmcnt ordering suffices).
// K/V prefetch issued right after staging barrier: covered by QK^T+
// softmax+PV (~600cyc) instead of PV only.
// Grid (bh, itile): 256 % 8 == 0 -> all 5 i-tiles of a bh land on one XCD.
__global__ __launch_bounds__(256) void k_fattn(
    const ushort* __restrict__ qk, const ushort* __restrict__ vt,
    const float* __restrict__ relb, ushort* __restrict__ ao)
{
  __shared__ alignas(16) ushort lk[64 * 64];
  __shared__ alignas(16) ushort lv[64 * 64];
  __shared__ alignas(16) ushort lp[128 * 64];
  __shared__ ushort lbias16[1280];     // bf16 bias at +64 offset, pad-safe
  const int tid = threadIdx.x, wv = tid >> 6, lane = tid & 63;
  const int quad = lane >> 4, c16 = lane & 15;
  const int bh = blockIdx.x, b = bh >> 3, h = bh & 7;
  const int i0 = blockIdx.y * 128, wm = wv * 32;
  for (int t = tid; t < 1280; t += 256) {
    int idx = t - 64;
    lbias16[t] = (idx >= 0 && idx < 1153) ? bf16bits(relb[idx]) : (ushort)0;
  }
  // Q fragments in registers for the whole block (rows wm+ms*16+c16)
  bf16x8 aq[2][2];
  #pragma unroll
  for (int ms = 0; ms < 2; ++ms) {
    int gi = i0 + wm + ms * 16 + c16; if (gi > 576) gi = 576;
    const ushort* qp = qk + ((size_t)(b * NN + gi)) * 1024 + h * 64;
    #pragma unroll
    for (int kk = 0; kk < 2; ++kk)
      aq[ms][kk] = *(const bf16x8*)(qp + (kk * 4 + quad) * 8);
  }
  const int s_r = tid >> 3, s_c = tid & 7;
  const ushort* kbase = qk + ((size_t)b * NN) * 1024 + 512 + h * 64 + s_c * 8;
  const ushort* vbase = vt + ((size_t)bh * 64) * 640 + s_c * 8;

  float lsum[2] = {0.f, 0.f};
  f32x4 z4 = {0.f, 0.f, 0.f, 0.f};
  f32x4 accp[2][4], accb[2][4];
  #pragma unroll
  for (int ms = 0; ms < 2; ++ms)
    #pragma unroll
    for (int ns = 0; ns < 4; ++ns) { accp[ms][ns] = z4; accb[ms][ns] = z4; }

  // preload tile jt=0 (j = 0..63, no clamp needed)
  u16x8 sk[2], sv[2];
  #pragma unroll
  for (int it = 0; it < 2; ++it) {
    int r = it * 32 + s_r;
    sk[it] = *(const u16x8*)(kbase + (size_t)r * 1024);
    sv[it] = *(const u16x8*)(vbase + (size_t)r * 640);
  }

  for (int jt = 0; jt < 10; ++jt) {
    __syncthreads();                       // prior lk/lv readers done
    #pragma unroll
    for (int it = 0; it < 2; ++it) {
      int r = it * 32 + s_r;
      int pc = (s_c ^ (r & 7)) * 8;
      *(u16x8*)(lk + r * 64 + pc) = sk[it];
      *(u16x8*)(lv + r * 64 + pc) = sv[it];
    }
    __syncthreads();                       // staging visible
    // issue next K/V tile loads NOW: latency hides under QK^T+softmax+PV
    if (jt < 9) {
      const int j0n = (jt + 1) * 64;
      #pragma unroll
      for (int it = 0; it < 2; ++it) {
        int r = it * 32 + s_r;
        int gj = j0n + r; if (gj > 576) gj = 576;
        sk[it] = *(const u16x8*)(kbase + (size_t)gj * 1024);
        sv[it] = *(const u16x8*)(vbase + (size_t)r * 640 + j0n);
      }
    }
    // ---- S^T = K Q^T, one ms (16 q-rows) at a time; softmax fused per ms
    #pragma unroll
    for (int ms = 0; ms < 2; ++ms) {
      f32x4 dacc[4] = {z4, z4, z4, z4};
      #pragma unroll
      for (int kk = 0; kk < 2; ++kk) {
        const int ck = kk * 4 + quad;
        #pragma unroll
        for (int ns = 0; ns < 4; ++ns) {
          const int row = ns * 16 + c16;
          bf16x8 bk = *(const bf16x8*)(lk + row * 64 + ((ck ^ (row & 7)) * 8));
          dacc[ns] = __builtin_amdgcn_mfma_f32_16x16x32_bf16(bk, aq[ms][kk], dacc[ns], 0, 0, 0);
        }
      }
      // lane holds S[i = wm+ms*16+c16][j = j0 + ns*16 + quad*4 + r]
      const int irow = wm + ms * 16 + c16;
      const int xr = irow & 7;
      #pragma unroll
      for (int ns = 0; ns < 4; ++ns) {
        float ex[4];
        #pragma unroll
        for (int r = 0; r < 4; ++r) {
          float e = __builtin_amdgcn_exp2f(dacc[ns][r]);
          if (jt == 9 && (ns * 16 + quad * 4 + r) >= 1) e = 0.f;   // j >= 577
          ex[r] = e;
        }
        lsum[ms] += (ex[0] + ex[1]) + (ex[2] + ex[3]);
        unsigned int p0 = (unsigned int)bf16bits(ex[0]) | ((unsigned int)bf16bits(ex[1]) << 16);
        unsigned int p1 = (unsigned int)bf16bits(ex[2]) | ((unsigned int)bf16bits(ex[3]) << 16);
        u32x2 pw = {p0, p1};
        const int lc = ns * 2 + (quad >> 1);         // logical 8-col chunk
        *(u32x2*)(lp + irow * 64 + ((lc ^ xr) * 8) + (quad & 1) * 4) = pw;
      }
    }
    // (no barrier: each wave reads only its own lp rows; lgkmcnt orders)
    // ---- O += P~ V  and  O_b += Bias V
    const int j0 = jt * 64;
    #pragma unroll
    for (int kk = 0; kk < 2; ++kk) {
      const int ck = kk * 4 + quad;
      bf16x8 ap[2], ab[2];
      #pragma unroll
      for (int ms = 0; ms < 2; ++ms) {
        const int row = wm + ms * 16 + c16;
        ap[ms] = *(const bf16x8*)(lp + row * 64 + ((ck ^ (row & 7)) * 8));
        u16x8 abu;
        const int base = 64 + 576 + j0 + kk * 32 + quad * 8 - (i0 + row);
        #pragma unroll
        for (int e = 0; e < 8; ++e) abu[e] = lbias16[base + e];
        ab[ms] = __builtin_bit_cast(bf16x8, abu);
      }
      #pragma unroll
      for (int ns = 0; ns < 4; ++ns) {
        const int row = ns * 16 + c16;
        bf16x8 bV = *(const bf16x8*)(lv + row * 64 + ((ck ^ (row & 7)) * 8));
        #pragma unroll
        for (int ms = 0; ms < 2; ++ms) {
          accp[ms][ns] = __builtin_amdgcn_mfma_f32_16x16x32_bf16(ap[ms], bV, accp[ms][ns], 0, 0, 0);
          accb[ms][ns] = __builtin_amdgcn_mfma_f32_16x16x32_bf16(ab[ms], bV, accb[ms][ns], 0, 0, 0);
        }
      }
    }
  }
  // ---- epilogue: row sums live per-lane for row c16; reduce across quads,
  // then shfl the needed row's total (rows quad*4+r of the output C-layout).
  float tot[2];
  #pragma unroll
  for (int ms = 0; ms < 2; ++ms) {
    float t = lsum[ms];
    t += __shfl_xor(t, 16);
    t += __shfl_xor(t, 32);
    tot[ms] = t;
  }
  #pragma unroll
  for (int ms = 0; ms < 2; ++ms) {
    #pragma unroll
    for (int r = 0; r < 4; ++r) {
      float li = 1.f / __shfl(tot[ms], quad * 4 + r);
      int ii = i0 + wm + ms * 16 + quad * 4 + r;
      if (ii < 577) {
        #pragma unroll
        for (int ns = 0; ns < 4; ++ns)
          ao[((size_t)(b * NN + ii)) * 512 + h * 64 + ns * 16 + c16] =
              bf16bits(accp[ms][ns][r] * li + accb[ms][ns][r]);
      }
    }
  }
}

// ---------------- out GEMM: ao[18464,512] @ Wout_t[512,512]^T + b_out -----
__global__ __launch_bounds__(256) void k_out(
    const ushort* __restrict__ A, const ushort* __restrict__ Bt,
    const float* __restrict__ bout, float* __restrict__ out)
{
  __shared__ alignas(16) ushort lA[128 * 40];
  __shared__ alignas(16) ushort lB[128 * 40];
  const int tid = threadIdx.x, wv = tid >> 6, lane = tid & 63;
  const int quad = lane >> 4, c16 = lane & 15;
  const int row0 = blockIdx.y * 128, n0 = blockIdx.x * 128;
  const int wm = (wv >> 1) * 64, wn = (wv & 1) * 64;
  f32x4 z4 = {0.f, 0.f, 0.f, 0.f};
  f32x4 acc[4][4];
  #pragma unroll
  for (int mi = 0; mi < 4; ++mi)
    #pragma unroll
    for (int ni = 0; ni < 4; ++ni) acc[mi][ni] = z4;

  for (int kt = 0; kt < 16; ++kt) {
    const int k0 = kt * 32;
    u16x8 sa[2], sb[2];
    #pragma unroll
    for (int it = 0; it < 2; ++it) {
      int ch = it * 256 + tid;
      int r = ch >> 2, cc = ch & 3;
      int grow = row0 + r; if (grow > BN - 1) grow = BN - 1;
      sa[it] = *(const u16x8*)(A + (size_t)grow * 512 + k0 + cc * 8);
      sb[it] = *(const u16x8*)(Bt + (size_t)(n0 + r) * 512 + k0 + cc * 8);
    }
    __syncthreads();
    #pragma unroll
    for (int it = 0; it < 2; ++it) {
      int ch = it * 256 + tid;
      int r = ch >> 2, cc = ch & 3;
      *(u16x8*)(lA + r * 40 + cc * 8) = sa[it];
      *(u16x8*)(lB + r * 40 + cc * 8) = sb[it];
    }
    __syncthreads();
    bf16x8 af[4], bfv[4];
    #pragma unroll
    for (int mi = 0; mi < 4; ++mi)
      af[mi] = *(const bf16x8*)(lA + (wm + mi * 16 + c16) * 40 + quad * 8);
    #pragma unroll
    for (int ni = 0; ni < 4; ++ni)
      bfv[ni] = *(const bf16x8*)(lB + (wn + ni * 16 + c16) * 40 + quad * 8);
    #pragma unroll
    for (int mi = 0; mi < 4; ++mi)
      #pragma unroll
      for (int ni = 0; ni < 4; ++ni)
        acc[mi][ni] = __builtin_amdgcn_mfma_f32_16x16x32_bf16(af[mi], bfv[ni], acc[mi][ni], 0, 0, 0);
  }
  #pragma unroll
  for (int mi = 0; mi < 4; ++mi) {
    #pragma unroll
    for (int r = 0; r < 4; ++r) {
      int grow = row0 + wm + mi * 16 + quad * 4 + r;
      if (grow < BN) {
        #pragma unroll
        for (int ni = 0; ni < 4; ++ni) {
          int col = n0 + wn + ni * 16 + c16;
          out[(size_t)grow * 512 + col] = acc[mi][ni][r] + bout[col];
        }
      }
    }
  }
}

// ---------------- launch ----------------
extern "C" void kernel_launch(void* const* d_in, const int* in_sizes, int n_in,
                              void* d_out, int out_size, void* d_ws, size_t ws_size,
                              hipStream_t stream) {
  (void)in_sizes; (void)n_in; (void)out_size;
  if (ws_size < WS_NEEDED) return;   // fail clean, not crash
  const float* x    = (const float*)d_in[0];
  const float* Wqk  = (const float*)d_in[1];
  const float* Wv   = (const float*)d_in[2];
  const float* Wout = (const float*)d_in[3];
  const float* bout = (const float*)d_in[4];
  const float* relb = (const float*)d_in[5];
  const float* edel = (const float*)d_in[6];
  const float* ealp = (const float*)d_in[7];
  const float* ebet = (const float*)d_in[8];
  const float* egam = (const float*)d_in[9];
  const float* eome = (const float*)d_in[10];

  char* ws = (char*)d_ws;
  ushort* Wqkvt = (ushort*)(ws + OFF_WQKVT);
  ushort* Woutt = (ushort*)(ws + OFF_WOUTT);
  float*  qtab  = (float*)(ws + OFF_QTAB);
  float*  ctab  = (float*)(ws + OFF_CTAB);
  ushort* qkb   = (ushort*)(ws + OFF_QK);
  ushort* vb    = (ushort*)(ws + OFF_V);
  ushort* xm    = (ushort*)(ws + OFF_XM);
  ushort* vtb   = (ushort*)(ws + OFF_VT);
  ushort* aob   = (ushort*)(ws + OFF_AO);
  float*  stf   = (float*)(ws + OFF_ST);       // EMA chunk states (dead before fattn)
  float*  outp  = (float*)d_out;

  k_prep<<<dim3(4160), dim3(256), 0, stream>>>(edel, ealp, ebet, egam, Wqk, Wv, Wout,
                                               qtab, ctab, Wqkvt, Woutt);
  k_ema_p1<<<dim3(16, 7, 32), dim3(64), 0, stream>>>(x, qtab, stf);
  k_ema_mid<<<dim3(2048), dim3(256), 0, stream>>>(qtab, stf);
  k_ema_fuse<<<dim3(8, 8, 32), dim3(64), 0, stream>>>(x, qtab, ctab, stf, eome, xm);
  k_qkv<<<dim3(12, 145), dim3(256), 0, stream>>>(xm, Wqkvt, qkb, vb);
  k_vtrans<<<dim3(10, 256), dim3(256), 0, stream>>>(vb, vtb);
  k_fattn<<<dim3(256, 5), dim3(256), 0, stream>>>(qkb, vtb, relb, aob);
  k_out<<<dim3(4, 145), dim3(256), 0, stream>>>(aob, Woutt, bout, outp);
}

// Round 6
// 299.758 us; speedup vs baseline: 1.3769x; 1.0223x over previous
//
#include <hip/hip_runtime.h>

typedef unsigned short ushort;

typedef __bf16 bf16x8 __attribute__((ext_vector_type(8)));
typedef float  f32x4  __attribute__((ext_vector_type(4)));
typedef unsigned short u16x8 __attribute__((ext_vector_type(8)));
typedef unsigned short u16x4 __attribute__((ext_vector_type(4)));
typedef unsigned int   u32x2 __attribute__((ext_vector_type(2)));

static constexpr int BB   = 32;
static constexpr int NN   = 577;   // N = NP+1
static constexpr int LL   = 576;   // NP
static constexpr int DIMC = 512;
static constexpr int BN   = BB * NN;  // 18464

// ---------------- workspace arena (bytes), total 98,828,288 (~94.3 MB) -----
// EMA chunk-states (16.8 MB) live in the AO region (dead until k_fattn).
static constexpr size_t SZ_WQKVT = 1536ull * 512 * 2;
static constexpr size_t SZ_WOUTT = 512ull * 512 * 2;
static constexpr size_t SZ_QK    = (size_t)BN * 1024 * 2;    // 37,814,272
static constexpr size_t SZ_V     = (size_t)BN * 512 * 2;     // 18,907,136
static constexpr size_t SZ_VT    = 256ull * 64 * 640 * 2;    // 20,971,520
static constexpr size_t OFF_WQKVT = 0;
static constexpr size_t OFF_WOUTT = OFF_WQKVT + SZ_WQKVT;
static constexpr size_t OFF_QTAB  = OFF_WOUTT + SZ_WOUTT;
static constexpr size_t OFF_CTAB  = OFF_QTAB + 65536;
static constexpr size_t OFF_QK    = OFF_CTAB + 65536;
static constexpr size_t OFF_V     = OFF_QK + SZ_QK;
static constexpr size_t OFF_REGION= OFF_V + SZ_V;
static constexpr size_t OFF_XM    = OFF_REGION;              // xm dead after k_qkv
static constexpr size_t OFF_VT    = OFF_REGION;              // vt overlays xm
static constexpr size_t OFF_AO    = OFF_REGION + SZ_VT;
static constexpr size_t OFF_ST    = OFF_AO;                  // EMA states overlay ao
static constexpr size_t WS_NEEDED = OFF_AO + SZ_V;           // 98,828,288

// ---------------- helpers ----------------
__device__ __forceinline__ ushort bf16bits(float f) {
  unsigned int u = __builtin_bit_cast(unsigned int, f);
  u = (u + 0x7fffu + ((u >> 16) & 1u)) >> 16;
  return (ushort)u;
}
// RNE bf16 pair-pack: same bits as (bf16bits(lo) | bf16bits(hi)<<16) but
// 5 VALU (2x bfe+add3 + v_perm byte-select) instead of ~9.
__device__ __forceinline__ unsigned int bf16pk(float lo, float hi) {
  unsigned int u0 = __builtin_bit_cast(unsigned int, lo);
  unsigned int u1 = __builtin_bit_cast(unsigned int, hi);
  unsigned int a0 = u0 + 0x7fffu + ((u0 >> 16) & 1u);
  unsigned int a1 = u1 + 0x7fffu + ((u1 >> 16) & 1u);
  return __builtin_amdgcn_perm(a1, a0, 0x07060302);   // {a1.hi16, a0.hi16}
}
__device__ __forceinline__ float sigmoidf_(float z) { return 1.f / (1.f + __expf(-z)); }
__device__ __forceinline__ float siluf(float z)     { return z / (1.f + __expf(-z)); }
// async global->LDS, 16B per lane; lds base must be wave-uniform (dest =
// base + lane*16, linear). Source address is per-lane (pre-swizzled).
__device__ __forceinline__ void gload16(const ushort* g, ushort* l) {
  __builtin_amdgcn_global_load_lds(
      (const __attribute__((address_space(1))) unsigned int*)g,
      (__attribute__((address_space(3))) unsigned int*)l, 16, 0, 0);
}

// ---------------- prep: EMA tables + bf16 transposed weights ----------------
__global__ __launch_bounds__(256) void k_prep(
    const float* __restrict__ delta, const float* __restrict__ alpha,
    const float* __restrict__ beta,  const float* __restrict__ gamma,
    const float* __restrict__ Wqk,   const float* __restrict__ Wv,
    const float* __restrict__ Wout,
    float* __restrict__ qtab, float* __restrict__ ctab,
    ushort* __restrict__ Wqkvt, ushort* __restrict__ Woutt)
{
  int idx = blockIdx.x * 256 + threadIdx.x;
  if (idx < 16384) {
    float p = sigmoidf_(delta[idx]);
    float q = 1.f - p * sigmoidf_(alpha[idx]);
    qtab[idx] = q;
    ctab[idx] = p * beta[idx] * gamma[idx] * 0.25f;   // scale = sqrt(1/16)
  }
  int i2 = idx - 16384;                                // Wqkv_t: [1536][512]
  if (i2 >= 0 && i2 < 1536 * 512) {
    int n = i2 >> 9, k = i2 & 511;
    float w = (n < 1024) ? Wqk[k * 1024 + n] : Wv[k * 512 + (n - 1024)];
    Wqkvt[i2] = bf16bits(w);
  }
  int i3 = i2 - 1536 * 512;                            // Wout_t: [512][512]
  if (i3 >= 0 && i3 < 512 * 512) {
    int n = i3 >> 9, k = i3 & 511;
    Woutt[i3] = bf16bits(Wout[k * 512 + n]);
  }
}

// ======== chunked EMA scan: h_t = q h_{t-1} + x_t is LINEAR, q in (0,1) ====
// 8 chunks of 72 steps. p1: per-chunk local end-state (h_in=0), chunks 0-6
// per direction. mid: exclusive scan of states with q^72. fuse: one block
// per (d-group, row-chunk, b) runs the BACKWARD pass (y2 -> fp16 LDS), then
// the FORWARD pass, combining y1+y2+x*omega, silu, bf16 -> xm directly.
// st layout: [(dir*32+b)*8 + chunk][n(16)][d(512)] floats.

// ---- pass 1: chunk-local final states, chunks 0..6 each direction --------
__global__ __launch_bounds__(64) void k_ema_p1(
    const float* __restrict__ x, const float* __restrict__ qtab,
    float* __restrict__ st)
{
  const int gx = blockIdx.x, cy = blockIdx.y, b = blockIdx.z;
  if (gx < 8) {
    const int d = gx * 64 + threadIdx.x;
    float q[16], h[16];
    #pragma unroll
    for (int n = 0; n < 16; ++n) { q[n] = qtab[d*16+n]; h[n] = 0.f; }
    const float* xp = x + ((size_t)b * NN + 1) * DIMC + d;
    const int blo = cy * 9;
    float xn[8];
    #pragma unroll
    for (int u = 0; u < 8; ++u) xn[u] = xp[(blo * 8 + u) * DIMC];
    for (int blk = blo; blk < blo + 9; ++blk) {
      float xv[8];
      #pragma unroll
      for (int u = 0; u < 8; ++u) xv[u] = xn[u];
      if (blk < blo + 8) {
        #pragma unroll
        for (int u = 0; u < 8; ++u) xn[u] = xp[((blk + 1) * 8 + u) * DIMC];
      }
      #pragma unroll
      for (int u = 0; u < 8; ++u) {
        float xx = xv[u];
        #pragma unroll
        for (int n = 0; n < 16; ++n) h[n] = fmaf(q[n], h[n], xx);
      }
    }
    float* sp = st + (((size_t)b * 8 + cy) * 16) * 512 + d;
    #pragma unroll
    for (int n = 0; n < 16; ++n) sp[n * 512] = h[n];
  } else {
    const int d = (gx - 8) * 64 + threadIdx.x;
    float q[16], g[16];
    #pragma unroll
    for (int n = 0; n < 16; ++n) { q[n] = qtab[(d+512)*16+n]; g[n] = 0.f; }
    const float* xp = x + ((size_t)b * NN + 1) * DIMC + d;
    const int blo = (7 - cy) * 9;
    float xn[8];
    #pragma unroll
    for (int u = 0; u < 8; ++u) xn[u] = xp[((blo + 8) * 8 + u) * DIMC];
    for (int blk = blo + 8; blk >= blo; --blk) {
      float xv[8];
      #pragma unroll
      for (int u = 0; u < 8; ++u) xv[u] = xn[u];
      if (blk > blo) {
        #pragma unroll
        for (int u = 0; u < 8; ++u) xn[u] = xp[((blk - 1) * 8 + u) * DIMC];
      }
      #pragma unroll
      for (int u = 7; u >= 0; --u) {
        float xx = xv[u];
        #pragma unroll
        for (int n = 0; n < 16; ++n) g[n] = fmaf(q[n], g[n], xx);
      }
    }
    float* sp = st + (((size_t)(32 + b) * 8 + cy) * 16) * 512 + d;
    #pragma unroll
    for (int n = 0; n < 16; ++n) sp[n * 512] = g[n];
  }
}

// ---- mid: exclusive scan over chunk states with q^72 ----------------------
__global__ __launch_bounds__(256) void k_ema_mid(
    const float* __restrict__ qtab, float* __restrict__ st)
{
  int idx = blockIdx.x * 256 + threadIdx.x;   // 524,288 = 64*16*512
  int d = idx & 511;
  int rest = idx >> 9;          // db*16 + n
  int n = rest & 15;
  int db = rest >> 4;           // dir*32 + b
  int dir = db >> 5;
  float q = qtab[(((size_t)dir << 9) + d) * 16 + n];
  float q2 = q * q, q4 = q2 * q2, q8 = q4 * q4;
  float q16 = q8 * q8, q32 = q16 * q16, q64 = q32 * q32;
  float qL = q64 * q8;          // q^72
  float h = 0.f;
  float* sp = st + ((size_t)db * 128 + n) * 512 + d;
  #pragma unroll
  for (int c = 0; c < 8; ++c) {
    float tmp = (c < 7) ? sp[c * 8192] : 0.f;   // chunk stride 16*512
    sp[c * 8192] = h;
    h = fmaf(qL, h, tmp);
  }
}

// ---- fused pass 3: bwd (y2->LDS fp16) then fwd + combine + silu -> xm -----
__global__ __launch_bounds__(64) void k_ema_fuse(
    const float* __restrict__ x, const float* __restrict__ qtab,
    const float* __restrict__ ctab, const float* __restrict__ st,
    const float* __restrict__ omega, ushort* __restrict__ xm)
{
  __shared__ _Float16 yb[72 * 64];   // 9,216 B -> 16 blocks/CU
  const int lane = threadIdx.x;
  const int gx = blockIdx.x, cy = blockIdx.y, b = blockIdx.z;
  const int d = gx * 64 + lane;
  const float* xp = x + ((size_t)b * NN + 1 + cy * 72) * DIMC + d;
  { // backward pass over this chunk's 72 rows
    float q[16], c[16], g[16];
    const float* sp = st + (((size_t)(32 + b) * 8 + (7 - cy)) * 16) * 512 + d;
    #pragma unroll
    for (int n = 0; n < 16; ++n) {
      q[n] = qtab[(d + 512) * 16 + n];
      c[n] = ctab[(d + 512) * 16 + n];
      g[n] = sp[n * 512];
    }
    float xn[8];
    #pragma unroll
    for (int u = 0; u < 8; ++u) xn[u] = xp[(64 + u) * DIMC];
    for (int blk = 8; blk >= 0; --blk) {
      float xv[8];
      #pragma unroll
      for (int u = 0; u < 8; ++u) xv[u] = xn[u];
      if (blk > 0) {
        #pragma unroll
        for (int u = 0; u < 8; ++u) xn[u] = xp[((blk - 1) * 8 + u) * DIMC];
      }
      #pragma unroll
      for (int u = 7; u >= 0; --u) {
        float xx = xv[u], y = 0.f;
        #pragma unroll
        for (int n = 0; n < 16; ++n) { g[n] = fmaf(q[n], g[n], xx); y = fmaf(c[n], g[n], y); }
        yb[(blk * 8 + u) * 64 + lane] = (_Float16)y;
      }
    }
  }
  __syncthreads();
  { // forward pass + combine
    float q[16], c[16], h[16];
    const float* sp = st + (((size_t)b * 8 + cy) * 16) * 512 + d;
    #pragma unroll
    for (int n = 0; n < 16; ++n) {
      q[n] = qtab[d * 16 + n];
      c[n] = ctab[d * 16 + n];
      h[n] = sp[n * 512];
    }
    const float om = omega[d];
    ushort* op = xm + ((size_t)b * NN + 1 + cy * 72) * DIMC + d;
    float xn[8];
    #pragma unroll
    for (int u = 0; u < 8; ++u) xn[u] = xp[u * DIMC];
    for (int blk = 0; blk < 9; ++blk) {
      float xv[8];
      #pragma unroll
      for (int u = 0; u < 8; ++u) xv[u] = xn[u];
      if (blk < 8) {
        #pragma unroll
        for (int u = 0; u < 8; ++u) xn[u] = xp[((blk + 1) * 8 + u) * DIMC];
      }
      #pragma unroll
      for (int u = 0; u < 8; ++u) {
        float xx = xv[u], y = 0.f;
        #pragma unroll
        for (int n = 0; n < 16; ++n) { h[n] = fmaf(q[n], h[n], xx); y = fmaf(c[n], h[n], y); }
        float s = y + (float)yb[(blk * 8 + u) * 64 + lane] + xx * om;
        op[(blk * 8 + u) * DIMC] = bf16bits(siluf(s));
      }
    }
  }
  if (cy == 0) {   // cls row passthrough
    size_t e0 = ((size_t)b * NN) * DIMC + d;
    xm[e0] = bf16bits(x[e0]);
  }
}

// ---------------- QKV GEMM: xm[18464,512] @ Wqkv_t[1536,512]^T -------------
// global_load_lds staging (m151: +35% vs reg-staging at this tile): LDS is
// LINEAR [128][32]; bank-spread comes from pre-swizzling the global source
// column by (row&3) and XOR-ing the same on the MFMA read (rule: linear dest
// + inverse-swz source + swz read). q cols pre-scaled by 0.125*log2(e).
// XCD-chunked block remap (bijective, nwg=1740).
__global__ __launch_bounds__(256) void k_qkv(
    const ushort* __restrict__ A, const ushort* __restrict__ Bt,
    ushort* __restrict__ qk, ushort* __restrict__ v)
{
  __shared__ alignas(16) ushort lA[128 * 32];
  __shared__ alignas(16) ushort lB[128 * 32];
  const int tid = threadIdx.x, wv = tid >> 6, lane = tid & 63;
  const int quad = lane >> 4, c16 = lane & 15;
  const int fid = blockIdx.y * 12 + blockIdx.x;        // dispatch-order id
  const int xcd = fid & 7, ord = fid >> 3;             // nwg=1740: q=217,r=4
  const int wg  = (xcd < 4 ? xcd * 218 : 872 + (xcd - 4) * 217) + ord;
  const int row0 = (wg / 12) * 128, n0 = (wg % 12) * 128;
  const int wm = (wv >> 1) * 64, wn = (wv & 1) * 64;
  // staging: wave wv covers local rows [wv*32, wv*32+32), instr s = 16 rows.
  // lane -> local row wv*32+s*16+(lane>>2), chunk lane&3 (16B each).
  const int sr  = wv * 32 + (lane >> 2);
  const int scs = ((lane & 3) ^ (sr & 3)) * 8;         // source col swizzle
  int ga[2], gb[2];
  #pragma unroll
  for (int s = 0; s < 2; ++s) {
    int r = row0 + sr + s * 16; if (r > BN - 1) r = BN - 1;
    ga[s] = r;
    gb[s] = n0 + sr + s * 16;
  }
  const int xread = (quad ^ (c16 & 3)) * 8;            // MFMA read swizzle
  f32x4 z4 = {0.f, 0.f, 0.f, 0.f};
  f32x4 acc[4][4];
  #pragma unroll
  for (int mi = 0; mi < 4; ++mi)
    #pragma unroll
    for (int ni = 0; ni < 4; ++ni) acc[mi][ni] = z4;

  for (int kt = 0; kt < 16; ++kt) {
    const int k0 = kt * 32;
    __syncthreads();                 // prior MFMA reads done
    #pragma unroll
    for (int s = 0; s < 2; ++s) {
      gload16(A  + (size_t)ga[s] * 512 + k0 + scs, lA + (wv * 32 + s * 16) * 32);
      gload16(Bt + (size_t)gb[s] * 512 + k0 + scs, lB + (wv * 32 + s * 16) * 32);
    }
    __syncthreads();                 // vmcnt drained -> tile visible
    bf16x8 af[4], bfv[4];
    #pragma unroll
    for (int mi = 0; mi < 4; ++mi)
      af[mi] = *(const bf16x8*)(lA + (wm + mi * 16 + c16) * 32 + xread);
    #pragma unroll
    for (int ni = 0; ni < 4; ++ni)
      bfv[ni] = *(const bf16x8*)(lB + (wn + ni * 16 + c16) * 32 + xread);
    #pragma unroll
    for (int mi = 0; mi < 4; ++mi)
      #pragma unroll
      for (int ni = 0; ni < 4; ++ni)
        acc[mi][ni] = __builtin_amdgcn_mfma_f32_16x16x32_bf16(af[mi], bfv[ni], acc[mi][ni], 0, 0, 0);
  }
  const bool isv = (n0 >= 1024);
  const float osc = (n0 < 512) ? 0.1803368801111f : 1.0f;  // 0.125*log2(e)
  #pragma unroll
  for (int mi = 0; mi < 4; ++mi) {
    #pragma unroll
    for (int r = 0; r < 4; ++r) {
      int grow = row0 + wm + mi * 16 + quad * 4 + r;
      if (grow < BN) {
        #pragma unroll
        for (int ni = 0; ni < 4; ++ni) {
          int col = n0 + wn + ni * 16 + c16;
          ushort vb = bf16bits(acc[mi][ni][r] * osc);
          if (!isv) qk[(size_t)grow * 1024 + col] = vb;
          else      v[(size_t)grow * 512 + (col - 1024)] = vb;
        }
      }
    }
  }
}

// ---------------- transpose v -> vt[bh*64+dh][640] (zero-padded j>=577) ----
__global__ __launch_bounds__(256) void k_vtrans(
    const ushort* __restrict__ v, ushort* __restrict__ vt)
{
  __shared__ alignas(16) ushort lt[64 * 72];
  const int tid = threadIdx.x;
  const int bh = blockIdx.y, b = bh >> 3, h = bh & 7;
  const int j0 = blockIdx.x * 64;
  #pragma unroll
  for (int pass = 0; pass < 2; ++pass) {
    int cch = pass * 256 + tid;
    int jl = cch >> 3, cc = cch & 7;
    int gj = j0 + jl;
    u16x8 val = {0, 0, 0, 0, 0, 0, 0, 0};
    if (gj < 577) val = *(const u16x8*)(v + ((size_t)(b * NN + gj)) * 512 + h * 64 + cc * 8);
    *(u16x8*)(lt + jl * 72 + cc * 8) = val;
  }
  __syncthreads();
  #pragma unroll
  for (int pass = 0; pass < 2; ++pass) {
    int cch = pass * 256 + tid;
    int dh = cch >> 3, jc = cch & 7;
    u16x8 o;
    #pragma unroll
    for (int e = 0; e < 8; ++e) o[e] = lt[(jc * 8 + e) * 72 + dh];
    *(u16x8*)(vt + ((size_t)(bh * 64 + dh)) * 640 + j0 + jc * 8) = o;
  }
}

// -------- fused flash attention: O = softmax(QK^T) V + Bias V --------------
// Static softmax; Q pre-scaled by 0.125*log2(e) -> raw exp2. Swapped QK^T
// (mfma(K,Q) -> S^T) + RNE pair-pack via v_perm (bf16pk: bit-identical to
// bf16bits, ~half the VALU) + 8-byte lp writes. 2 barriers/tile (each wave
// reads only its own lp rows). K/V prefetch issued right after staging
// barrier. Grid (bh, itile): all 5 i-tiles of a bh land on one XCD.
__global__ __launch_bounds__(256) void k_fattn(
    const ushort* __restrict__ qk, const ushort* __restrict__ vt,
    const float* __restrict__ relb, ushort* __restrict__ ao)
{
  __shared__ alignas(16) ushort lk[64 * 64];
  __shared__ alignas(16) ushort lv[64 * 64];
  __shared__ alignas(16) ushort lp[128 * 64];
  __shared__ ushort lbias16[1280];     // bf16 bias at +64 offset, pad-safe
  const int tid = threadIdx.x, wv = tid >> 6, lane = tid & 63;
  const int quad = lane >> 4, c16 = lane & 15;
  const int bh = blockIdx.x, b = bh >> 3, h = bh & 7;
  const int i0 = blockIdx.y * 128, wm = wv * 32;
  for (int t = tid; t < 1280; t += 256) {
    int idx = t - 64;
    lbias16[t] = (idx >= 0 && idx < 1153) ? bf16bits(relb[idx]) : (ushort)0;
  }
  // Q fragments in registers for the whole block (rows wm+ms*16+c16)
  bf16x8 aq[2][2];
  #pragma unroll
  for (int ms = 0; ms < 2; ++ms) {
    int gi = i0 + wm + ms * 16 + c16; if (gi > 576) gi = 576;
    const ushort* qp = qk + ((size_t)(b * NN + gi)) * 1024 + h * 64;
    #pragma unroll
    for (int kk = 0; kk < 2; ++kk)
      aq[ms][kk] = *(const bf16x8*)(qp + (kk * 4 + quad) * 8);
  }
  const int s_r = tid >> 3, s_c = tid & 7;
  const ushort* kbase = qk + ((size_t)b * NN) * 1024 + 512 + h * 64 + s_c * 8;
  const ushort* vbase = vt + ((size_t)bh * 64) * 640 + s_c * 8;

  float lsum[2] = {0.f, 0.f};
  f32x4 z4 = {0.f, 0.f, 0.f, 0.f};
  f32x4 accp[2][4], accb[2][4];
  #pragma unroll
  for (int ms = 0; ms < 2; ++ms)
    #pragma unroll
    for (int ns = 0; ns < 4; ++ns) { accp[ms][ns] = z4; accb[ms][ns] = z4; }

  // preload tile jt=0 (j = 0..63, no clamp needed)
  u16x8 sk[2], sv[2];
  #pragma unroll
  for (int it = 0; it < 2; ++it) {
    int r = it * 32 + s_r;
    sk[it] = *(const u16x8*)(kbase + (size_t)r * 1024);
    sv[it] = *(const u16x8*)(vbase + (size_t)r * 640);
  }

  for (int jt = 0; jt < 10; ++jt) {
    __syncthreads();                       // prior lk/lv readers done
    #pragma unroll
    for (int it = 0; it < 2; ++it) {
      int r = it * 32 + s_r;
      int pc = (s_c ^ (r & 7)) * 8;
      *(u16x8*)(lk + r * 64 + pc) = sk[it];
      *(u16x8*)(lv + r * 64 + pc) = sv[it];
    }
    __syncthreads();                       // staging visible
    // issue next K/V tile loads NOW: latency hides under QK^T+softmax+PV
    if (jt < 9) {
      const int j0n = (jt + 1) * 64;
      #pragma unroll
      for (int it = 0; it < 2; ++it) {
        int r = it * 32 + s_r;
        int gj = j0n + r; if (gj > 576) gj = 576;
        sk[it] = *(const u16x8*)(kbase + (size_t)gj * 1024);
        sv[it] = *(const u16x8*)(vbase + (size_t)r * 640 + j0n);
      }
    }
    // ---- S^T = K Q^T, one ms (16 q-rows) at a time; softmax fused per ms
    #pragma unroll
    for (int ms = 0; ms < 2; ++ms) {
      f32x4 dacc[4] = {z4, z4, z4, z4};
      #pragma unroll
      for (int kk = 0; kk < 2; ++kk) {
        const int ck = kk * 4 + quad;
        #pragma unroll
        for (int ns = 0; ns < 4; ++ns) {
          const int row = ns * 16 + c16;
          bf16x8 bk = *(const bf16x8*)(lk + row * 64 + ((ck ^ (row & 7)) * 8));
          dacc[ns] = __builtin_amdgcn_mfma_f32_16x16x32_bf16(bk, aq[ms][kk], dacc[ns], 0, 0, 0);
        }
      }
      // lane holds S[i = wm+ms*16+c16][j = j0 + ns*16 + quad*4 + r]
      const int irow = wm + ms * 16 + c16;
      const int xr = irow & 7;
      #pragma unroll
      for (int ns = 0; ns < 4; ++ns) {
        float ex[4];
        #pragma unroll
        for (int r = 0; r < 4; ++r) {
          float e = __builtin_amdgcn_exp2f(dacc[ns][r]);
          if (jt == 9 && (ns * 16 + quad * 4 + r) >= 1) e = 0.f;   // j >= 577
          ex[r] = e;
        }
        lsum[ms] += (ex[0] + ex[1]) + (ex[2] + ex[3]);
        u32x2 pw = { bf16pk(ex[0], ex[1]), bf16pk(ex[2], ex[3]) };
        const int lc = ns * 2 + (quad >> 1);         // logical 8-col chunk
        *(u32x2*)(lp + irow * 64 + ((lc ^ xr) * 8) + (quad & 1) * 4) = pw;
      }
    }
    // (no barrier: each wave reads only its own lp rows; lgkmcnt orders)
    // ---- O += P~ V  and  O_b += Bias V
    const int j0 = jt * 64;
    #pragma unroll
    for (int kk = 0; kk < 2; ++kk) {
      const int ck = kk * 4 + quad;
      bf16x8 ap[2], ab[2];
      #pragma unroll
      for (int ms = 0; ms < 2; ++ms) {
        const int row = wm + ms * 16 + c16;
        ap[ms] = *(const bf16x8*)(lp + row * 64 + ((ck ^ (row & 7)) * 8));
        u16x8 abu;
        const int base = 64 + 576 + j0 + kk * 32 + quad * 8 - (i0 + row);
        #pragma unroll
        for (int e = 0; e < 8; ++e) abu[e] = lbias16[base + e];
        ab[ms] = __builtin_bit_cast(bf16x8, abu);
      }
      #pragma unroll
      for (int ns = 0; ns < 4; ++ns) {
        const int row = ns * 16 + c16;
        bf16x8 bV = *(const bf16x8*)(lv + row * 64 + ((ck ^ (row & 7)) * 8));
        #pragma unroll
        for (int ms = 0; ms < 2; ++ms) {
          accp[ms][ns] = __builtin_amdgcn_mfma_f32_16x16x32_bf16(ap[ms], bV, accp[ms][ns], 0, 0, 0);
          accb[ms][ns] = __builtin_amdgcn_mfma_f32_16x16x32_bf16(ab[ms], bV, accb[ms][ns], 0, 0, 0);
        }
      }
    }
  }
  // ---- epilogue: row sums live per-lane for row c16; reduce across quads,
  // then shfl the needed row's total (rows quad*4+r of the output C-layout).
  float tot[2];
  #pragma unroll
  for (int ms = 0; ms < 2; ++ms) {
    float t = lsum[ms];
    t += __shfl_xor(t, 16);
    t += __shfl_xor(t, 32);
    tot[ms] = t;
  }
  #pragma unroll
  for (int ms = 0; ms < 2; ++ms) {
    #pragma unroll
    for (int r = 0; r < 4; ++r) {
      float li = 1.f / __shfl(tot[ms], quad * 4 + r);
      int ii = i0 + wm + ms * 16 + quad * 4 + r;
      if (ii < 577) {
        #pragma unroll
        for (int ns = 0; ns < 4; ++ns)
          ao[((size_t)(b * NN + ii)) * 512 + h * 64 + ns * 16 + c16] =
              bf16bits(accp[ms][ns][r] * li + accb[ms][ns][r]);
      }
    }
  }
}

// ---------------- out GEMM: ao[18464,512] @ Wout_t[512,512]^T + b_out -----
// Same global_load_lds staging + linear-LDS swizzle as k_qkv.
__global__ __launch_bounds__(256) void k_out(
    const ushort* __restrict__ A, const ushort* __restrict__ Bt,
    const float* __restrict__ bout, float* __restrict__ out)
{
  __shared__ alignas(16) ushort lA[128 * 32];
  __shared__ alignas(16) ushort lB[128 * 32];
  const int tid = threadIdx.x, wv = tid >> 6, lane = tid & 63;
  const int quad = lane >> 4, c16 = lane & 15;
  const int row0 = blockIdx.y * 128, n0 = blockIdx.x * 128;
  const int wm = (wv >> 1) * 64, wn = (wv & 1) * 64;
  const int sr  = wv * 32 + (lane >> 2);
  const int scs = ((lane & 3) ^ (sr & 3)) * 8;
  int ga[2], gb[2];
  #pragma unroll
  for (int s = 0; s < 2; ++s) {
    int r = row0 + sr + s * 16; if (r > BN - 1) r = BN - 1;
    ga[s] = r;
    gb[s] = n0 + sr + s * 16;
  }
  const int xread = (quad ^ (c16 & 3)) * 8;
  f32x4 z4 = {0.f, 0.f, 0.f, 0.f};
  f32x4 acc[4][4];
  #pragma unroll
  for (int mi = 0; mi < 4; ++mi)
    #pragma unroll
    for (int ni = 0; ni < 4; ++ni) acc[mi][ni] = z4;

  for (int kt = 0; kt < 16; ++kt) {
    const int k0 = kt * 32;
    __syncthreads();
    #pragma unroll
    for (int s = 0; s < 2; ++s) {
      gload16(A  + (size_t)ga[s] * 512 + k0 + scs, lA + (wv * 32 + s * 16) * 32);
      gload16(Bt + (size_t)gb[s] * 512 + k0 + scs, lB + (wv * 32 + s * 16) * 32);
    }
    __syncthreads();
    bf16x8 af[4], bfv[4];
    #pragma unroll
    for (int mi = 0; mi < 4; ++mi)
      af[mi] = *(const bf16x8*)(lA + (wm + mi * 16 + c16) * 32 + xread);
    #pragma unroll
    for (int ni = 0; ni < 4; ++ni)
      bfv[ni] = *(const bf16x8*)(lB + (wn + ni * 16 + c16) * 32 + xread);
    #pragma unroll
    for (int mi = 0; mi < 4; ++mi)
      #pragma unroll
      for (int ni = 0; ni < 4; ++ni)
        acc[mi][ni] = __builtin_amdgcn_mfma_f32_16x16x32_bf16(af[mi], bfv[ni], acc[mi][ni], 0, 0, 0);
  }
  #pragma unroll
  for (int mi = 0; mi < 4; ++mi) {
    #pragma unroll
    for (int r = 0; r < 4; ++r) {
      int grow = row0 + wm + mi * 16 + quad * 4 + r;
      if (grow < BN) {
        #pragma unroll
        for (int ni = 0; ni < 4; ++ni) {
          int col = n0 + wn + ni * 16 + c16;
          out[(size_t)grow * 512 + col] = acc[mi][ni][r] + bout[col];
        }
      }
    }
  }
}

// ---------------- launch ----------------
extern "C" void kernel_launch(void* const* d_in, const int* in_sizes, int n_in,
                              void* d_out, int out_size, void* d_ws, size_t ws_size,
                              hipStream_t stream) {
  (void)in_sizes; (void)n_in; (void)out_size;
  if (ws_size < WS_NEEDED) return;   // fail clean, not crash
  const float* x    = (const float*)d_in[0];
  const float* Wqk  = (const float*)d_in[1];
  const float* Wv   = (const float*)d_in[2];
  const float* Wout = (const float*)d_in[3];
  const float* bout = (const float*)d_in[4];
  const float* relb = (const float*)d_in[5];
  const float* edel = (const float*)d_in[6];
  const float* ealp = (const float*)d_in[7];
  const float* ebet = (const float*)d_in[8];
  const float* egam = (const float*)d_in[9];
  const float* eome = (const float*)d_in[10];

  char* ws = (char*)d_ws;
  ushort* Wqkvt = (ushort*)(ws + OFF_WQKVT);
  ushort* Woutt = (ushort*)(ws + OFF_WOUTT);
  float*  qtab  = (float*)(ws + OFF_QTAB);
  float*  ctab  = (float*)(ws + OFF_CTAB);
  ushort* qkb   = (ushort*)(ws + OFF_QK);
  ushort* vb    = (ushort*)(ws + OFF_V);
  ushort* xm    = (ushort*)(ws + OFF_XM);
  ushort* vtb   = (ushort*)(ws + OFF_VT);
  ushort* aob   = (ushort*)(ws + OFF_AO);
  float*  stf   = (float*)(ws + OFF_ST);       // EMA chunk states (dead before fattn)
  float*  outp  = (float*)d_out;

  k_prep<<<dim3(4160), dim3(256), 0, stream>>>(edel, ealp, ebet, egam, Wqk, Wv, Wout,
                                               qtab, ctab, Wqkvt, Woutt);
  k_ema_p1<<<dim3(16, 7, 32), dim3(64), 0, stream>>>(x, qtab, stf);
  k_ema_mid<<<dim3(2048), dim3(256), 0, stream>>>(qtab, stf);
  k_ema_fuse<<<dim3(8, 8, 32), dim3(64), 0, stream>>>(x, qtab, ctab, stf, eome, xm);
  k_qkv<<<dim3(12, 145), dim3(256), 0, stream>>>(xm, Wqkvt, qkb, vb);
  k_vtrans<<<dim3(10, 256), dim3(256), 0, stream>>>(vb, vtb);
  k_fattn<<<dim3(256, 5), dim3(256), 0, stream>>>(qkb, vtb, relb, aob);
  k_out<<<dim3(4, 145), dim3(256), 0, stream>>>(aob, Woutt, bout, outp);
}